// Round 2
// baseline (903.656 us; speedup 1.0000x reference)
//
#include <hip/hip_runtime.h>
#include <math.h>

#define BATCH   16384
#define DIMS    64
#define WID     128
#define KN      8
#define NP      23        // 3*KN - 1
#define NCOL    (DIMS * NP)   // 1472 param columns
#define NLAYERS 8
#define BI_F    4.0f

#define PF_WOUT (NLAYERS * NCOL * WID)        // per-flow Wout elems: 1,507,328
#define PF_W1   (NLAYERS * WID * DIMS)        // per-flow W1 elems:   65,536

typedef short s16x8 __attribute__((ext_vector_type(8)));
typedef float f32x4 __attribute__((ext_vector_type(4)));

__device__ __forceinline__ unsigned short f2bf(float f) {
    unsigned int u = __builtin_bit_cast(unsigned int, f);
    unsigned int r = (u + 0x7FFFu + ((u >> 16) & 1u)) >> 16;
    return (unsigned short)r;
}
__device__ __forceinline__ float bf2f(unsigned short u) {
    return __builtin_bit_cast(float, (unsigned int)u << 16);
}
__device__ __forceinline__ float softplusf(float v) {
    return fmaxf(v, 0.0f) + __logf(1.0f + __expf(-fabsf(v)));
}

// ---------------------------------------------------------------------------
// Pre-mask MADE weights -> bf16 workspace (identical to proven 886us version)
// plus zero-init of ldf/ldg (atomicAdd targets; harness poisons out buffer).
// ---------------------------------------------------------------------------
__global__ __launch_bounds__(256) void premask_kernel(
    const float* __restrict__ f_wout, const float* __restrict__ g_wout,
    const float* __restrict__ f_w1,   const float* __restrict__ g_w1,
    unsigned short* __restrict__ womask, unsigned short* __restrict__ w1mask,
    float* __restrict__ ldf, float* __restrict__ ldg)
{
    const int idx    = blockIdx.x * 256 + threadIdx.x;
    const int stride = gridDim.x * 256;

    const int totw = 2 * PF_WOUT;
    for (int i = idx; i < totw; i += stride) {
        int fl = i / PF_WOUT;
        int r  = i % PF_WOUT;
        int h  = r % WID;
        int o  = (r / WID) % NCOL;
        int d  = o / NP;
        int hd = h % (DIMS - 1) + 1;            // hid_deg
        const float* src = fl ? g_wout : f_wout;
        womask[i] = (hd <= d) ? f2bf(src[r]) : (unsigned short)0;
    }

    const int tot1 = 2 * PF_W1;
    for (int i = idx; i < tot1; i += stride) {
        int fl = i / PF_W1;
        int r  = i % PF_W1;
        int c  = r % DIMS;
        int w  = (r / DIMS) % WID;
        int deg = w % (DIMS - 1) + 1;           // hid_deg
        const float* src = fl ? g_w1 : f_w1;
        w1mask[i] = (c < deg) ? f2bf(src[r]) : (unsigned short)0;
    }

    for (int i = idx; i < BATCH; i += stride) {
        ldf[i] = 0.0f;
        ldg[i] = 0.0f;
    }
}

// ---------------------------------------------------------------------------
// One MAF layer. Grid (BATCH/64, 4): blockIdx.y = flow + 2*dhalf. Block = 4
// waves, 64 batch rows; each wave owns 16 rows and 32 dims (8 groups of 4).
// NO barriers (all dataflow wave-private; Hs/Pc separate arrays; Pc written
// and read as u16 so the compiler sees the dependency).
//   GEMM1 (MFMA 16x16x32): H = relu(x @ W1m^T + b1) -> LDS Hs (row-major).
//   Per 4-dim group gg: 6 MFMA n-tiles over UNPADDED cols [92*gg, 92*gg+96)
//   (4 overlap cols staged but never read) -> Pc col-major pitch-18, then
//   spline for 4 dims (lane = (b=m, dim-in-group=q)) in registers.
// ---------------------------------------------------------------------------
__global__ __launch_bounds__(256, 4) void layer_kernel(
    const float* __restrict__ xin_f, const float* __restrict__ xin_g,
    float* __restrict__ xout_f,      float* __restrict__ xout_g,
    const unsigned short* __restrict__ w1m_f, const unsigned short* __restrict__ w1m_g,
    const float* __restrict__ b1_f,  const float* __restrict__ b1_g,
    const unsigned short* __restrict__ wom_f, const unsigned short* __restrict__ wom_g,
    const float* __restrict__ bo_f,  const float* __restrict__ bo_g,
    float* __restrict__ ld_f,        float* __restrict__ ld_g)
{
    // Hs: H tile, row-major [16][136] u16 per wave (b128-friendly pitch).
    __shared__ __align__(16) unsigned short Hs[4][16 * 136];
    // Pc: P staging, col-major 96 cols x 18 shorts (16 rows + 2 pad) per wave.
    __shared__ __align__(16) unsigned short Pc[4][96 * 18];

    const int t     = threadIdx.x;
    const int wv    = t >> 6;          // wave 0..3
    const int ln    = t & 63;
    const int m     = ln & 15;         // row-in-tile / col-in-tile index
    const int q     = ln >> 4;         // quad
    const int flow  = blockIdx.y & 1;
    const int dhalf = blockIdx.y >> 1; // dim half: groups [dhalf*8, dhalf*8+8)
    const int r0    = blockIdx.x * 64 + wv * 16;   // this wave's first batch row

    const float* xin          = flow ? xin_g : xin_f;
    float*       xout         = flow ? xout_g : xout_f;
    const unsigned short* w1m = flow ? w1m_g : w1m_f;
    const float* b1           = flow ? b1_g  : b1_f;
    const unsigned short* wom = flow ? wom_g : wom_f;
    const float* bo           = flow ? bo_g  : bo_f;
    float*       ldp          = flow ? ld_g  : ld_f;

    // ---- GEMM1: A-frags from x (global, fp32 -> bf16) ----
    const float* xrow = xin + (size_t)(r0 + m) * DIMS;
    s16x8 xa[2];
    #pragma unroll
    for (int ks = 0; ks < 2; ++ks) {
        float4 v0 = *(const float4*)(xrow + ks * 32 + q * 8);
        float4 v1 = *(const float4*)(xrow + ks * 32 + q * 8 + 4);
        s16x8 a;
        a[0] = (short)f2bf(v0.x); a[1] = (short)f2bf(v0.y);
        a[2] = (short)f2bf(v0.z); a[3] = (short)f2bf(v0.w);
        a[4] = (short)f2bf(v1.x); a[5] = (short)f2bf(v1.y);
        a[6] = (short)f2bf(v1.z); a[7] = (short)f2bf(v1.w);
        xa[ks] = a;
    }

    f32x4 hacc[8];
    #pragma unroll
    for (int nt = 0; nt < 8; ++nt) {
        float bv = b1[nt * 16 + m];
        hacc[nt] = (f32x4){bv, bv, bv, bv};
    }
    #pragma unroll
    for (int ks = 0; ks < 2; ++ks) {
        #pragma unroll
        for (int nt = 0; nt < 8; ++nt) {
            s16x8 bfr = *(const s16x8*)(w1m + (nt * 16 + m) * DIMS + ks * 32 + q * 8);
            hacc[nt] = __builtin_amdgcn_mfma_f32_16x16x32_bf16(xa[ks], bfr, hacc[nt], 0, 0, 0);
        }
    }
    // ReLU -> bf16 -> Hs. Lane holds col (h = nt*16+m), rows q*4+rr.
    unsigned short* hs = &Hs[wv][0];
    #pragma unroll
    for (int nt = 0; nt < 8; ++nt) {
        #pragma unroll
        for (int rr = 0; rr < 4; ++rr) {
            hs[(q * 4 + rr) * 136 + nt * 16 + m] = f2bf(fmaxf(hacc[nt][rr], 0.0f));
        }
    }
    asm volatile("" ::: "memory");   // pin Hs stores before af loads

    // ---- A-frags for GEMM2 from Hs (b128 reads, wave-private) ----
    s16x8 af[4];
    #pragma unroll
    for (int ks = 0; ks < 4; ++ks)
        af[ks] = *(const s16x8*)&hs[m * 136 + ks * 32 + q * 8];

    unsigned short* pcm = &Pc[wv][0];
    float ldsum = 0.0f;

    #pragma unroll 1
    for (int gl = 0; gl < 8; ++gl) {
        const int gg   = dhalf * 8 + gl;       // global 4-dim group 0..15
        const int base = gg * 92;              // unpadded col base (dims gg*4..+3)

        // ---- GEMM2 group: 6 tiles over cols [base, base+96) ----
        f32x4 acc[6];
        #pragma unroll
        for (int nt = 0; nt < 6; ++nt) {
            int o = base + nt * 16 + m;
            o = (o < NCOL) ? o : (NCOL - 1);   // clamp: stay inside input buffer
            float bv = bo[o];
            acc[nt] = (f32x4){bv, bv, bv, bv};
        }
        #pragma unroll
        for (int ks = 0; ks < 4; ++ks) {
            #pragma unroll
            for (int nt = 0; nt < 6; ++nt) {
                // col up to base+95 may spill past this layer's slice for the
                // last group; stays inside the workspace allocation (harmless,
                // those Pc columns are never read).
                const s16x8 bfr = *(const s16x8*)(wom +
                    (size_t)(base + nt * 16 + m) * WID + ks * 32 + q * 8);
                acc[nt] = __builtin_amdgcn_mfma_f32_16x16x32_bf16(af[ks], bfr, acc[nt], 0, 0, 0);
            }
        }
        // P -> Pc col-major (pitch 18): lane col u = nt*16+m, rows q*4..q*4+3.
        // Plain u16 stores (same type as the reads below -> compiler-visible
        // dependency; adjacent pairs merge to b32 legally).
        #pragma unroll
        for (int nt = 0; nt < 6; ++nt) {
            const int c18 = (nt * 16 + m) * 18 + q * 4;
            #pragma unroll
            for (int rr = 0; rr < 4; ++rr)
                pcm[c18 + rr] = f2bf(acc[nt][rr]);
        }

        // ---- spline: 4 dims x 16 rows, lane = (b=m, dim-in-group=q) ----
        {
            const int d = gg * 4 + q;            // global dim
            const int b = m;                     // row within wave

            float pp[NP];
            #pragma unroll
            for (int j = 0; j < NP; ++j)
                pp[j] = bf2f(pcm[(q * 23 + j) * 18 + b]);

            const float xraw = xin[(size_t)(r0 + b) * DIMS + d];

            float mw = pp[0], mh = pp[8];
            #pragma unroll
            for (int j = 1; j < KN; ++j) {
                mw = fmaxf(mw, pp[j]);
                mh = fmaxf(mh, pp[8 + j]);
            }
            float ew[KN], eh[KN];
            float sw = 0.0f, sh = 0.0f;
            #pragma unroll
            for (int j = 0; j < KN; ++j) {
                ew[j] = __expf(pp[j] - mw);      sw += ew[j];
                eh[j] = __expf(pp[8 + j] - mh);  sh += eh[j];
            }
            const float cmul = 8.0f / 1.01f;     // 2*Bi/(1+ADJ)
            const float rw = 1.0f / sw, rh = 1.0f / sh;
            float width[KN], height[KN];
            #pragma unroll
            for (int j = 0; j < KN; ++j) {
                width[j]  = (ew[j] * rw + 0.00125f) * cmul;
                height[j] = (eh[j] * rh + 0.00125f) * cmul;
            }
            float dv[KN + 1];
            dv[0] = 1.0f; dv[KN] = 1.0f;
            #pragma unroll
            for (int i = 1; i < KN; ++i) dv[i] = softplusf(pp[15 + i]) + 0.001f;

            const bool inside = (xraw > -BI_F) && (xraw < BI_F);
            const float xcl = fminf(fmaxf(xraw, -BI_F), BI_F);

            float cx = -BI_F, cy = -BI_F;
            float xk = -BI_F, yk = -BI_F, xk1 = 0.f, yk1 = 0.f, dk = 1.f, dk1 = 1.f;
            #pragma unroll
            for (int i = 0; i < KN; ++i) {
                const float nx = cx + width[i];
                const float ny = cy + height[i];
                const bool cc = (xcl >= cx);
                xk  = cc ? cx : xk;    yk  = cc ? cy : yk;
                xk1 = cc ? nx : xk1;   yk1 = cc ? ny : yk1;
                dk  = cc ? dv[i] : dk; dk1 = cc ? dv[i + 1] : dk1;
                cx = nx; cy = ny;
            }

            const float invw = 1.0f / (xk1 - xk);
            const float sk   = (yk1 - yk) * invw;
            const float xi   = (xcl - xk) * invw;
            const float omx  = 1.0f - xi;
            const float den  = sk + (dk1 + dk - 2.0f * sk) * xi * omx;
            float outv = yk + (yk1 - yk) * (sk * xi * xi + dk * xi * omx) / den;
            const float numl = dk1 * xi * xi + 2.0f * sk * xi * omx + dk * omx * omx;
            float ldj = 2.0f * __logf(sk) + __logf(numl) - 2.0f * __logf(den);
            outv = inside ? outv : xraw;
            ldj  = inside ? ldj : 0.0f;

            xout[(size_t)(r0 + b) * DIMS + (DIMS - 1 - d)] = outv;
            ldsum += ldj;
        }
    }

    // ---- ld reduce across the 4 lanes sharing each b (q=0..3), then one
    //      atomicAdd per (row, flow, dhalf) into the zero-initialized output.
    float v = ldsum + __shfl_xor(ldsum, 16, 64);
    v = v + __shfl_xor(v, 32, 64);
    if (ln < 16) {
        atomicAdd(ldp + (r0 + ln), v);
    }
}

// ---------------------------------------------------------------------------
extern "C" void kernel_launch(void* const* d_in, const int* in_sizes, int n_in,
                              void* d_out, int out_size, void* d_ws, size_t ws_size,
                              hipStream_t stream)
{
    const float* x      = (const float*)d_in[0];
    const float* y      = (const float*)d_in[1];
    const float* f_W1   = (const float*)d_in[2];
    const float* f_b1   = (const float*)d_in[3];
    const float* f_Wout = (const float*)d_in[4];
    const float* f_bout = (const float*)d_in[5];
    const float* g_W1   = (const float*)d_in[6];
    const float* g_b1   = (const float*)d_in[7];
    const float* g_Wout = (const float*)d_in[8];
    const float* g_bout = (const float*)d_in[9];

    float* out = (float*)d_out;
    float* xo  = out;                               // [B, D]
    float* ldf = out + (size_t)BATCH * DIMS;        // [B]
    float* yo  = ldf + BATCH;                       // [B, D]
    float* ldg = yo + (size_t)BATCH * DIMS;         // [B]

    // Workspace layout: identical footprint to the proven 886us version.
    unsigned short* womask = (unsigned short*)d_ws;           // 2*PF_WOUT bf16
    unsigned short* w1mask = womask + 2 * (size_t)PF_WOUT;    // 2*PF_W1 bf16
    float* xA_f = (float*)(w1mask + 2 * (size_t)PF_W1);       // [B,D] ping (f)
    float* xA_g = xA_f + (size_t)BATCH * DIMS;                // [B,D] ping (g)

    premask_kernel<<<dim3(2048), dim3(256), 0, stream>>>(
        f_Wout, g_Wout, f_W1, g_W1, womask, w1mask, ldf, ldg);

    for (int l = 0; l < NLAYERS; ++l) {
        const float* inf = (l == 0) ? x : ((l & 1) ? xA_f : xo);
        const float* ing = (l == 0) ? y : ((l & 1) ? xA_g : yo);
        float* outf = (l & 1) ? xo : xA_f;
        float* outg = (l & 1) ? yo : xA_g;

        layer_kernel<<<dim3(BATCH / 64, 4), dim3(256), 0, stream>>>(
            inf, ing, outf, outg,
            w1mask + (size_t)l * WID * DIMS,
            w1mask + (size_t)PF_W1 + (size_t)l * WID * DIMS,
            f_b1 + (size_t)l * WID, g_b1 + (size_t)l * WID,
            womask + (size_t)l * NCOL * WID,
            womask + (size_t)PF_WOUT + (size_t)l * NCOL * WID,
            f_bout + (size_t)l * NCOL, g_bout + (size_t)l * NCOL,
            ldf, ldg);
    }
}

// Round 4
// 508.948 us; speedup vs baseline: 1.7755x; 1.7755x over previous
//
#include <hip/hip_runtime.h>
#include <math.h>

#define BATCH   16384
#define DIMS    64
#define WID     128
#define KN      8
#define NP      23        // 3*KN - 1
#define NCOL    (DIMS * NP)   // 1472 param columns
#define NLAYERS 8
#define BI_F    4.0f
#define GRP     92        // param cols per 4-dim group
#define NGRP    16        // groups per row

#define PF_WOUT (NLAYERS * NCOL * WID)        // per-flow Wout elems: 1,507,328
#define PF_W1   (NLAYERS * WID * DIMS)        // per-flow W1 elems:   65,536

typedef short s16x8 __attribute__((ext_vector_type(8)));
typedef float f32x4 __attribute__((ext_vector_type(4)));

__device__ __forceinline__ unsigned short f2bf(float f) {
    unsigned int u = __builtin_bit_cast(unsigned int, f);
    unsigned int r = (u + 0x7FFFu + ((u >> 16) & 1u)) >> 16;
    return (unsigned short)r;
}
__device__ __forceinline__ float bf2f(unsigned short u) {
    return __builtin_bit_cast(float, (unsigned int)u << 16);
}
__device__ __forceinline__ float softplusf(float v) {
    return fmaxf(v, 0.0f) + __logf(1.0f + __expf(-fabsf(v)));
}

// global -> LDS direct DMA, 16B per lane. LDS dest is wave-uniform base +
// lane*16 (HW rule); global src is per-lane.
__device__ __forceinline__ void stage16(const unsigned short* g, unsigned short* l) {
    __builtin_amdgcn_global_load_lds(
        (__attribute__((address_space(1))) void*)g,
        (__attribute__((address_space(3))) void*)l,
        16, 0, 0);
}

// ---------------------------------------------------------------------------
// Pre-mask MADE weights -> bf16 workspace. womask is stored K-SWIZZLED within
// each 128-short column: k -> k ^ ((col&7)<<4). The linear global_load_lds
// then lands the swizzled layout in LDS, and the ds_read_b128 B-fragment
// reads (which XOR the same key) are 2-way-conflict-free. Swizzle keeps
// 8-short runs contiguous (key has no bits <4), so fragment order is intact.
// ---------------------------------------------------------------------------
__global__ __launch_bounds__(256) void premask_kernel(
    const float* __restrict__ f_wout, const float* __restrict__ g_wout,
    const float* __restrict__ f_w1,   const float* __restrict__ g_w1,
    unsigned short* __restrict__ womask, unsigned short* __restrict__ w1mask)
{
    const int idx    = blockIdx.x * 256 + threadIdx.x;
    const int stride = gridDim.x * 256;

    const int totw = 2 * PF_WOUT;
    for (int i = idx; i < totw; i += stride) {
        int fl = i / PF_WOUT;
        int r  = i % PF_WOUT;
        int h  = r % WID;
        int o  = (r / WID) % NCOL;              // layer-local param col
        int d  = o / NP;
        int hd = h % (DIMS - 1) + 1;            // hid_deg
        const float* src = fl ? g_wout : f_wout;
        unsigned short v = (hd <= d) ? f2bf(src[r]) : (unsigned short)0;
        const int dst = i - h + (h ^ ((o & 7) << 4));   // swizzled k position
        womask[dst] = v;
    }

    const int tot1 = 2 * PF_W1;
    for (int i = idx; i < tot1; i += stride) {
        int fl = i / PF_W1;
        int r  = i % PF_W1;
        int c  = r % DIMS;
        int w  = (r / DIMS) % WID;
        int deg = w % (DIMS - 1) + 1;           // hid_deg
        const float* src = fl ? g_w1 : f_w1;
        w1mask[i] = (c < deg) ? f2bf(src[r]) : (unsigned short)0;
    }
}

// ---------------------------------------------------------------------------
// One MAF layer. Grid (BATCH/64, 2): blockIdx.y = flow. Block = 4 waves,
// 64 batch rows; each wave owns 16 rows; all 64 dims = 16 groups of 4.
//
// Weight pipeline: GEMM2's B-tiles (96 cols x 128 k bf16 = 24 KB/group) are
// DMA-staged into a double-buffered LDS tile once per BLOCK via
// global_load_lds, prefetched one group ahead so the VMEM latency hides
// under the previous group's MFMA+spline. Previously every wave streamed
// these from L2/L3 with ~1 load in flight -> latency-serial (the invariant
// 110us across rounds 0/2).
// ---------------------------------------------------------------------------
__global__ __launch_bounds__(256, 2) void layer_kernel(
    const float* __restrict__ xin_f, const float* __restrict__ xin_g,
    float* __restrict__ xout_f,      float* __restrict__ xout_g,
    const unsigned short* __restrict__ w1m_f, const unsigned short* __restrict__ w1m_g,
    const float* __restrict__ b1_f,  const float* __restrict__ b1_g,
    const unsigned short* __restrict__ wom_f, const unsigned short* __restrict__ wom_g,
    const float* __restrict__ bo_f,  const float* __restrict__ bo_g,
    float* __restrict__ ld_f,        float* __restrict__ ld_g,
    int layer)
{
    // Wl: double-buffered staged weight tile, [buf][col 0..95][k 0..127]
    //     (k swizzled by ((global_col)&7)<<4, baked into womask).  49,152 B
    __shared__ __align__(16) unsigned short Wl[2][96 * 128];
    // Hs: H tile, row-major [16][136] u16 per wave.                17,408 B
    __shared__ __align__(16) unsigned short Hs[4][16 * 136];
    // Pc: P staging, col-major 96 cols x 18 shorts per wave.       13,824 B
    __shared__ __align__(16) unsigned short Pc[4][96 * 18];
    // total 80,384 B -> 2 blocks/CU

    const int t    = threadIdx.x;
    const int wv   = t >> 6;          // wave 0..3
    const int ln   = t & 63;
    const int m    = ln & 15;         // row-in-tile / col-in-tile index
    const int q    = ln >> 4;         // quad
    const int flow = blockIdx.y;
    const int r0   = blockIdx.x * 64 + wv * 16;   // this wave's first batch row

    const float* xin          = flow ? xin_g : xin_f;
    float*       xout         = flow ? xout_g : xout_f;
    const unsigned short* w1m = flow ? w1m_g : w1m_f;
    const float* b1           = flow ? b1_g  : b1_f;
    const unsigned short* wom = flow ? wom_g : wom_f;
    const float* bo           = flow ? bo_g  : bo_f;
    float*       ldp          = flow ? ld_g  : ld_f;

    unsigned short* wl_cur = &Wl[0][0];
    unsigned short* wl_nxt = &Wl[1][0];

    // ---- prologue: DMA-stage group 0 weights (24 chunks of 1KB; wave wv
    //      owns cols [wv*24, wv*24+24)). Fire-and-forget; drained by the
    //      __syncthreads() below, hidden under GEMM1.
    {
        const unsigned short* src = wom + ((size_t)wv * 24) * WID + ln * 8;
        unsigned short* dst = wl_cur + (wv * 24) * WID;
        #pragma unroll
        for (int i = 0; i < 6; ++i)
            stage16(src + i * 512, dst + i * 512);
    }

    // ---- hoist all 16 spline x-inputs for this lane (one per group) ----
    float xr[NGRP];
    #pragma unroll
    for (int g = 0; g < NGRP; ++g)
        xr[g] = xin[(size_t)(r0 + m) * DIMS + g * 4 + q];

    // ---- GEMM1: A-frags from x (global, fp32 -> bf16) ----
    const float* xrow = xin + (size_t)(r0 + m) * DIMS;
    s16x8 xa[2];
    #pragma unroll
    for (int ks = 0; ks < 2; ++ks) {
        float4 v0 = *(const float4*)(xrow + ks * 32 + q * 8);
        float4 v1 = *(const float4*)(xrow + ks * 32 + q * 8 + 4);
        s16x8 a;
        a[0] = (short)f2bf(v0.x); a[1] = (short)f2bf(v0.y);
        a[2] = (short)f2bf(v0.z); a[3] = (short)f2bf(v0.w);
        a[4] = (short)f2bf(v1.x); a[5] = (short)f2bf(v1.y);
        a[6] = (short)f2bf(v1.z); a[7] = (short)f2bf(v1.w);
        xa[ks] = a;
    }

    f32x4 hacc[8];
    #pragma unroll
    for (int nt = 0; nt < 8; ++nt) {
        float bv = b1[nt * 16 + m];
        hacc[nt] = (f32x4){bv, bv, bv, bv};
    }
    #pragma unroll
    for (int ks = 0; ks < 2; ++ks) {
        #pragma unroll
        for (int nt = 0; nt < 8; ++nt) {
            s16x8 bfr = *(const s16x8*)(w1m + (nt * 16 + m) * DIMS + ks * 32 + q * 8);
            hacc[nt] = __builtin_amdgcn_mfma_f32_16x16x32_bf16(xa[ks], bfr, hacc[nt], 0, 0, 0);
        }
    }
    // ReLU -> bf16 -> Hs. Lane holds col (h = nt*16+m), rows q*4+rr.
    unsigned short* hs = &Hs[wv][0];
    #pragma unroll
    for (int nt = 0; nt < 8; ++nt) {
        #pragma unroll
        for (int rr = 0; rr < 4; ++rr) {
            hs[(q * 4 + rr) * 136 + nt * 16 + m] = f2bf(fmaxf(hacc[nt][rr], 0.0f));
        }
    }
    asm volatile("" ::: "memory");   // pin Hs stores before af loads

    // ---- A-frags for GEMM2 from Hs (b128 reads, wave-private) ----
    s16x8 af[4];
    #pragma unroll
    for (int ks = 0; ks < 4; ++ks)
        af[ks] = *(const s16x8*)&hs[m * 136 + ks * 32 + q * 8];

    // ---- bias prefetch for group 0 ----
    float bnx[6];
    #pragma unroll
    for (int nt = 0; nt < 6; ++nt) {
        int o = nt * 16 + m;
        o = (o < NCOL) ? o : (NCOL - 1);
        bnx[nt] = bo[o];
    }

    unsigned short* pcm = &Pc[wv][0];
    float ldsum = 0.0f;

    __syncthreads();                 // group-0 weights resident for all waves

    #pragma unroll 1
    for (int g = 0; g < NGRP; ++g) {
        // ---- GEMM2 group g from LDS (swizzled): cols [92g, 92g+96) ----
        f32x4 acc[6];
        #pragma unroll
        for (int nt = 0; nt < 6; ++nt)
            acc[nt] = (f32x4){bnx[nt], bnx[nt], bnx[nt], bnx[nt]};

        const int swz = ((g * 4 + m) & 7) << 4;   // (92g + nt*16 + m) & 7 == (4g+m)&7
        #pragma unroll
        for (int ks = 0; ks < 4; ++ks) {
            #pragma unroll
            for (int nt = 0; nt < 6; ++nt) {
                const s16x8 bfr = *(const s16x8*)&wl_cur[
                    (nt * 16 + m) * WID + ((ks * 32 + q * 8) ^ swz)];
                acc[nt] = __builtin_amdgcn_mfma_f32_16x16x32_bf16(af[ks], bfr, acc[nt], 0, 0, 0);
            }
        }

        // ---- prefetch group g+1: DMA weights + bias (latency hides under
        //      the spline below; drained at the barrier).
        if (g < NGRP - 1) {
            const unsigned short* src = wom +
                ((size_t)(g + 1) * GRP + wv * 24) * WID + ln * 8;
            unsigned short* dst = wl_nxt + (wv * 24) * WID;
            #pragma unroll
            for (int i = 0; i < 6; ++i)
                stage16(src + i * 512, dst + i * 512);
            #pragma unroll
            for (int nt = 0; nt < 6; ++nt) {
                int o = (g + 1) * GRP + nt * 16 + m;
                o = (o < NCOL) ? o : (NCOL - 1);
                bnx[nt] = bo[o];
            }
        }

        // P -> Pc col-major (pitch 18): lane col u = nt*16+m, rows q*4..q*4+3.
        #pragma unroll
        for (int nt = 0; nt < 6; ++nt) {
            const int c18 = (nt * 16 + m) * 18 + q * 4;
            #pragma unroll
            for (int rr = 0; rr < 4; ++rr)
                pcm[c18 + rr] = f2bf(acc[nt][rr]);
        }

        // ---- spline: 4 dims x 16 rows, lane = (b=m, dim-in-group=q) ----
        {
            const int d = g * 4 + q;             // global dim

            float pp[NP];
            #pragma unroll
            for (int j = 0; j < NP; ++j)
                pp[j] = bf2f(pcm[(q * 23 + j) * 18 + m]);

            const float xraw = xr[g];

            // softmax WITHOUT max-subtraction: |P| is bounded (~O(1)) by the
            // 0.05-scaled network, far from exp overflow; ratio is identical.
            float ew[KN], eh[KN];
            #pragma unroll
            for (int j = 0; j < KN; ++j) {
                ew[j] = __expf(pp[j]);
                eh[j] = __expf(pp[8 + j]);
            }
            const float sw = ((ew[0] + ew[1]) + (ew[2] + ew[3]))
                           + ((ew[4] + ew[5]) + (ew[6] + ew[7]));
            const float sh = ((eh[0] + eh[1]) + (eh[2] + eh[3]))
                           + ((eh[4] + eh[5]) + (eh[6] + eh[7]));
            const float cmul = 8.0f / 1.01f;     // 2*Bi/(1+ADJ)
            const float cadd = 0.00125f * (8.0f / 1.01f);
            const float rw = cmul / sw, rh = cmul / sh;
            float width[KN], height[KN];
            #pragma unroll
            for (int j = 0; j < KN; ++j) {
                width[j]  = fmaf(ew[j], rw, cadd);
                height[j] = fmaf(eh[j], rh, cadd);
            }
            float dv[KN + 1];
            dv[0] = 1.0f; dv[KN] = 1.0f;
            #pragma unroll
            for (int i = 1; i < KN; ++i) dv[i] = softplusf(pp[15 + i]) + 0.001f;

            const bool inside = (xraw > -BI_F) && (xraw < BI_F);
            const float xcl = fminf(fmaxf(xraw, -BI_F), BI_F);

            float cx = -BI_F, cy = -BI_F;
            float xk = -BI_F, yk = -BI_F, xk1 = 0.f, yk1 = 0.f, dk = 1.f, dk1 = 1.f;
            #pragma unroll
            for (int i = 0; i < KN; ++i) {
                const float nx = cx + width[i];
                const float ny = cy + height[i];
                const bool cc = (xcl >= cx);
                xk  = cc ? cx : xk;    yk  = cc ? cy : yk;
                xk1 = cc ? nx : xk1;   yk1 = cc ? ny : yk1;
                dk  = cc ? dv[i] : dk; dk1 = cc ? dv[i + 1] : dk1;
                cx = nx; cy = ny;
            }

            const float invw = 1.0f / (xk1 - xk);
            const float sk   = (yk1 - yk) * invw;
            const float xi   = (xcl - xk) * invw;
            const float omx  = 1.0f - xi;
            const float den  = sk + (dk1 + dk - 2.0f * sk) * xi * omx;
            const float rden = 1.0f / den;
            float outv = fmaf((yk1 - yk) * (sk * xi * xi + dk * xi * omx), rden, yk);
            const float numl = dk1 * xi * xi + 2.0f * sk * xi * omx + dk * omx * omx;
            // 2log(sk) + log(numl) - 2log(den) == log(sk^2 * numl * rden^2)
            float ldj = __logf(sk * sk * numl * rden * rden);
            outv = inside ? outv : xraw;
            ldj  = inside ? ldj : 0.0f;

            xout[(size_t)(r0 + m) * DIMS + (DIMS - 1 - d)] = outv;
            ldsum += ldj;
        }

        if (g < NGRP - 1) {
            __syncthreads();         // drains DMA (vmcnt) + all waves done with wl_cur
            unsigned short* tmp = wl_cur; wl_cur = wl_nxt; wl_nxt = tmp;
        }
    }

    // ---- ld reduce across the 4 lanes sharing each b (q=0..3) ----
    float v = ldsum + __shfl_xor(ldsum, 16, 64);
    v = v + __shfl_xor(v, 32, 64);
    if (ln < 16) {
        const int bg = r0 + ln;
        if (layer == 0) ldp[bg] = v;    // overwrite poison
        else            ldp[bg] += v;   // exclusive owner, stream-serialized
    }
}

// ---------------------------------------------------------------------------
extern "C" void kernel_launch(void* const* d_in, const int* in_sizes, int n_in,
                              void* d_out, int out_size, void* d_ws, size_t ws_size,
                              hipStream_t stream)
{
    const float* x      = (const float*)d_in[0];
    const float* y      = (const float*)d_in[1];
    const float* f_W1   = (const float*)d_in[2];
    const float* f_b1   = (const float*)d_in[3];
    const float* f_Wout = (const float*)d_in[4];
    const float* f_bout = (const float*)d_in[5];
    const float* g_W1   = (const float*)d_in[6];
    const float* g_b1   = (const float*)d_in[7];
    const float* g_Wout = (const float*)d_in[8];
    const float* g_bout = (const float*)d_in[9];

    float* out = (float*)d_out;
    float* xo  = out;                               // [B, D]
    float* ldf = out + (size_t)BATCH * DIMS;        // [B]
    float* yo  = ldf + BATCH;                       // [B, D]
    float* ldg = yo + (size_t)BATCH * DIMS;         // [B]

    // Workspace layout: identical footprint to the proven 886us version.
    unsigned short* womask = (unsigned short*)d_ws;           // 2*PF_WOUT bf16
    unsigned short* w1mask = womask + 2 * (size_t)PF_WOUT;    // 2*PF_W1 bf16
    float* xA_f = (float*)(w1mask + 2 * (size_t)PF_W1);       // [B,D] ping (f)
    float* xA_g = xA_f + (size_t)BATCH * DIMS;                // [B,D] ping (g)

    premask_kernel<<<dim3(2048), dim3(256), 0, stream>>>(
        f_Wout, g_Wout, f_W1, g_W1, womask, w1mask);

    for (int l = 0; l < NLAYERS; ++l) {
        const float* inf = (l == 0) ? x : ((l & 1) ? xA_f : xo);
        const float* ing = (l == 0) ? y : ((l & 1) ? xA_g : yo);
        float* outf = (l & 1) ? xo : xA_f;
        float* outg = (l & 1) ? yo : xA_g;

        layer_kernel<<<dim3(BATCH / 64, 2), dim3(256), 0, stream>>>(
            inf, ing, outf, outg,
            w1mask + (size_t)l * WID * DIMS,
            w1mask + (size_t)PF_W1 + (size_t)l * WID * DIMS,
            f_b1 + (size_t)l * WID, g_b1 + (size_t)l * WID,
            womask + (size_t)l * NCOL * WID,
            womask + (size_t)PF_WOUT + (size_t)l * NCOL * WID,
            f_bout + (size_t)l * NCOL, g_bout + (size_t)l * NCOL,
            ldf, ldg, l);
    }
}

// Round 5
// 499.481 us; speedup vs baseline: 1.8092x; 1.0190x over previous
//
#include <hip/hip_runtime.h>
#include <math.h>

#define BATCH   16384
#define DIMS    64
#define WID     128
#define KN      8
#define NP      23        // 3*KN - 1
#define NCOL    (DIMS * NP)   // 1472 param columns
#define NLAYERS 8
#define BI_F    4.0f
#define GRP     92        // param cols per 4-dim group
#define NGRPB   8         // groups per block (dhalf split)

#define PF_WOUT (NLAYERS * NCOL * WID)        // per-flow Wout elems: 1,507,328
#define PF_W1   (NLAYERS * WID * DIMS)        // per-flow W1 elems:   65,536

typedef short s16x8 __attribute__((ext_vector_type(8)));
typedef float f32x4 __attribute__((ext_vector_type(4)));

__device__ __forceinline__ unsigned short f2bf(float f) {
    unsigned int u = __builtin_bit_cast(unsigned int, f);
    unsigned int r = (u + 0x7FFFu + ((u >> 16) & 1u)) >> 16;
    return (unsigned short)r;
}
__device__ __forceinline__ float bf2f(unsigned short u) {
    return __builtin_bit_cast(float, (unsigned int)u << 16);
}
__device__ __forceinline__ float softplusf(float v) {
    return fmaxf(v, 0.0f) + __logf(1.0f + __expf(-fabsf(v)));
}

// global -> LDS direct DMA, 16B per lane. LDS dest is wave-uniform base +
// lane*16 (HW rule); global src is per-lane.
__device__ __forceinline__ void stage16(const unsigned short* g, unsigned short* l) {
    __builtin_amdgcn_global_load_lds(
        (__attribute__((address_space(1))) void*)g,
        (__attribute__((address_space(3))) void*)l,
        16, 0, 0);
}

// ---------------------------------------------------------------------------
// Pre-mask MADE weights -> bf16 workspace. womask is stored K-SWIZZLED within
// each 128-short column: k -> k ^ ((col&7)<<4). The linear global_load_lds
// then lands the swizzled layout in LDS, and the ds_read_b128 B-fragment
// reads (which XOR the same key) are conflict-light. Swizzle keeps 8-short
// runs contiguous (key has no bits <4), so fragment order is intact.
// Also zero-inits ldf/ldg (atomicAdd targets; harness poisons out buffer).
// ---------------------------------------------------------------------------
__global__ __launch_bounds__(256) void premask_kernel(
    const float* __restrict__ f_wout, const float* __restrict__ g_wout,
    const float* __restrict__ f_w1,   const float* __restrict__ g_w1,
    unsigned short* __restrict__ womask, unsigned short* __restrict__ w1mask,
    float* __restrict__ ldf, float* __restrict__ ldg)
{
    const int idx    = blockIdx.x * 256 + threadIdx.x;
    const int stride = gridDim.x * 256;

    const int totw = 2 * PF_WOUT;
    for (int i = idx; i < totw; i += stride) {
        int fl = i / PF_WOUT;
        int r  = i % PF_WOUT;
        int h  = r % WID;
        int o  = (r / WID) % NCOL;              // layer-local param col
        int d  = o / NP;
        int hd = h % (DIMS - 1) + 1;            // hid_deg
        const float* src = fl ? g_wout : f_wout;
        unsigned short v = (hd <= d) ? f2bf(src[r]) : (unsigned short)0;
        const int dst = i - h + (h ^ ((o & 7) << 4));   // swizzled k position
        womask[dst] = v;
    }

    const int tot1 = 2 * PF_W1;
    for (int i = idx; i < tot1; i += stride) {
        int fl = i / PF_W1;
        int r  = i % PF_W1;
        int c  = r % DIMS;
        int w  = (r / DIMS) % WID;
        int deg = w % (DIMS - 1) + 1;           // hid_deg
        const float* src = fl ? g_w1 : f_w1;
        w1mask[i] = (c < deg) ? f2bf(src[r]) : (unsigned short)0;
    }

    for (int i = idx; i < BATCH; i += stride) {
        ldf[i] = 0.0f;
        ldg[i] = 0.0f;
    }
}

// ---------------------------------------------------------------------------
// One MAF layer. Grid (BATCH/64, 4): blockIdx.y = flow + 2*dhalf. Block = 4
// waves, 64 batch rows, 32 dims (8 groups of 4). LDS = 40,960 B -> exactly
// 4 blocks/CU (163,840 B = 160 KiB), 4 waves/SIMD: barrier drains and dep
// chains of one block are overlapped by three co-resident blocks (the ~44%
// no-issue gap measured in round 4 at 2 blocks/CU).
//
// Wl is SINGLE-buffered (92 cols x 128 k = 23,552 B): per group,
//   MFMA(g) -> B1(all reads done) -> issue DMA(g+1) -> spline(g) hides the
//   DMA latency -> B2 (drains vmcnt) -> next group.
// S overlays Hs (GEMM1 H-tile, dead after af-frag loads) and Pc (P staging)
// as same-type u16 views of one array (compiler-visible aliasing).
// MFMA tile cols 92..95 read past Wl into S: finite bf16 garbage, isolated
// to P columns the spline never reads (MFMA dataflow is per-column).
// ---------------------------------------------------------------------------
__global__ __launch_bounds__(256, 4) void layer_kernel(
    const float* __restrict__ xin_f, const float* __restrict__ xin_g,
    float* __restrict__ xout_f,      float* __restrict__ xout_g,
    const unsigned short* __restrict__ w1m_f, const unsigned short* __restrict__ w1m_g,
    const float* __restrict__ b1_f,  const float* __restrict__ b1_g,
    const unsigned short* __restrict__ wom_f, const unsigned short* __restrict__ wom_g,
    const float* __restrict__ bo_f,  const float* __restrict__ bo_g,
    float* __restrict__ ld_f,        float* __restrict__ ld_g)
{
    // Wl: staged weight tile, linear [92 cols][128 k] (k pre-swizzled
    //     by ((global_col)&7)<<4, baked into womask).          23,552 B
    __shared__ __align__(16) unsigned short Wl[GRP * WID];
    // S: per-wave overlay. Hs view: [16 rows][136] (b128-aligned pitch,
    //    34 dwords -> conflict-free af reads). Pc view: col-major
    //    [96 cols][18] (16 rows + 2 pad). Hs dead before first Pc write.
    __shared__ __align__(16) unsigned short S[4][2176];
    // total 40,960 B

    const int t     = threadIdx.x;
    const int wv    = t >> 6;          // wave 0..3
    const int ln    = t & 63;
    const int m     = ln & 15;         // row-in-tile / col-in-tile index
    const int q     = ln >> 4;         // quad
    const int flow  = blockIdx.y & 1;
    const int dhalf = blockIdx.y >> 1; // dim half: groups [dhalf*8, dhalf*8+8)
    const int g0    = dhalf * NGRPB;
    const int r0    = blockIdx.x * 64 + wv * 16;   // this wave's first batch row

    const float* xin          = flow ? xin_g : xin_f;
    float*       xout         = flow ? xout_g : xout_f;
    const unsigned short* w1m = flow ? w1m_g : w1m_f;
    const float* b1           = flow ? b1_g  : b1_f;
    const unsigned short* wom = flow ? wom_g : wom_f;
    const float* bo           = flow ? bo_g  : bo_f;
    float*       ldp          = flow ? ld_g  : ld_f;

    // ---- prologue: DMA-stage group g0's 92-col slab (23 chunks of 1KB;
    //      wave wv takes chunks wv, wv+4, ... — wave-uniform addresses).
    //      Fire-and-forget; drained by the pre-loop barrier, hidden under
    //      GEMM1.
    {
        const unsigned short* src = wom + (size_t)g0 * GRP * WID + ln * 8;
        #pragma unroll
        for (int i = 0; i < 6; ++i) {
            const int c = wv + 4 * i;
            if (c < 23) stage16(src + c * 512, Wl + c * 512);
        }
    }

    // ---- hoist this block's 8 spline x-inputs for this lane ----
    float xr[NGRPB];
    #pragma unroll
    for (int g = 0; g < NGRPB; ++g)
        xr[g] = xin[(size_t)(r0 + m) * DIMS + (g0 + g) * 4 + q];

    // ---- GEMM1: A-frags from x (global, fp32 -> bf16) ----
    const float* xrow = xin + (size_t)(r0 + m) * DIMS;
    s16x8 xa[2];
    #pragma unroll
    for (int ks = 0; ks < 2; ++ks) {
        float4 v0 = *(const float4*)(xrow + ks * 32 + q * 8);
        float4 v1 = *(const float4*)(xrow + ks * 32 + q * 8 + 4);
        s16x8 a;
        a[0] = (short)f2bf(v0.x); a[1] = (short)f2bf(v0.y);
        a[2] = (short)f2bf(v0.z); a[3] = (short)f2bf(v0.w);
        a[4] = (short)f2bf(v1.x); a[5] = (short)f2bf(v1.y);
        a[6] = (short)f2bf(v1.z); a[7] = (short)f2bf(v1.w);
        xa[ks] = a;
    }

    f32x4 hacc[8];
    #pragma unroll
    for (int nt = 0; nt < 8; ++nt) {
        float bv = b1[nt * 16 + m];
        hacc[nt] = (f32x4){bv, bv, bv, bv};
    }
    #pragma unroll
    for (int ks = 0; ks < 2; ++ks) {
        #pragma unroll
        for (int nt = 0; nt < 8; ++nt) {
            s16x8 bfr = *(const s16x8*)(w1m + (nt * 16 + m) * DIMS + ks * 32 + q * 8);
            hacc[nt] = __builtin_amdgcn_mfma_f32_16x16x32_bf16(xa[ks], bfr, hacc[nt], 0, 0, 0);
        }
    }
    // ReLU -> bf16 -> Hs view of S. Lane holds col (h = nt*16+m), rows q*4+rr.
    unsigned short* sw = &S[wv][0];
    #pragma unroll
    for (int nt = 0; nt < 8; ++nt) {
        #pragma unroll
        for (int rr = 0; rr < 4; ++rr) {
            sw[(q * 4 + rr) * 136 + nt * 16 + m] = f2bf(fmaxf(hacc[nt][rr], 0.0f));
        }
    }
    asm volatile("" ::: "memory");   // pin Hs stores before af loads

    // ---- A-frags for GEMM2 from Hs (b128 reads, wave-private) ----
    s16x8 af[4];
    #pragma unroll
    for (int ks = 0; ks < 4; ++ks)
        af[ks] = *(const s16x8*)&sw[m * 136 + ks * 32 + q * 8];
    asm volatile("" ::: "memory");   // af read before Pc overwrites Hs

    // ---- bias prefetch for group g0 ----
    float bnx[6];
    #pragma unroll
    for (int nt = 0; nt < 6; ++nt) {
        int o = g0 * GRP + nt * 16 + m;
        o = (o < NCOL) ? o : (NCOL - 1);
        bnx[nt] = bo[o];
    }

    float ldsum = 0.0f;

    __syncthreads();                 // group-g0 weights resident for all waves

    #pragma unroll 1
    for (int gl = 0; gl < NGRPB; ++gl) {
        const int gg = g0 + gl;      // global 4-dim group

        // ---- GEMM2 group gg from LDS (swizzled): cols [92gg, 92gg+96) ----
        f32x4 acc[6];
        #pragma unroll
        for (int nt = 0; nt < 6; ++nt)
            acc[nt] = (f32x4){bnx[nt], bnx[nt], bnx[nt], bnx[nt]};

        const int swz = ((gg * 4 + m) & 7) << 4;  // (92gg+nt*16+m)&7 == (4gg+m)&7
        #pragma unroll
        for (int ks = 0; ks < 4; ++ks) {
            #pragma unroll
            for (int nt = 0; nt < 6; ++nt) {
                const s16x8 bfr = *(const s16x8*)&Wl[
                    (nt * 16 + m) * WID + ((ks * 32 + q * 8) ^ swz)];
                acc[nt] = __builtin_amdgcn_mfma_f32_16x16x32_bf16(af[ks], bfr, acc[nt], 0, 0, 0);
            }
        }

        if (gl < NGRPB - 1) {
            __syncthreads();         // B1: all waves done reading Wl(gg)
            // ---- issue DMA for group gg+1 into the same buffer; latency
            //      hides under the spline below; drained at B2.
            const unsigned short* src = wom + (size_t)(gg + 1) * GRP * WID + ln * 8;
            #pragma unroll
            for (int i = 0; i < 6; ++i) {
                const int c = wv + 4 * i;
                if (c < 23) stage16(src + c * 512, Wl + c * 512);
            }
            #pragma unroll
            for (int nt = 0; nt < 6; ++nt) {
                int o = (gg + 1) * GRP + nt * 16 + m;
                o = (o < NCOL) ? o : (NCOL - 1);
                bnx[nt] = bo[o];
            }
        }

        // P -> Pc view of S, col-major (pitch 18): lane col u = nt*16+m,
        // rows q*4..q*4+3 (u16 stores; consecutive rr merge to b64).
        #pragma unroll
        for (int nt = 0; nt < 6; ++nt) {
            const int c18 = (nt * 16 + m) * 18 + q * 4;
            #pragma unroll
            for (int rr = 0; rr < 4; ++rr)
                sw[c18 + rr] = f2bf(acc[nt][rr]);
        }

        // ---- spline: 4 dims x 16 rows, lane = (b=m, dim-in-group=q) ----
        {
            const int d = gg * 4 + q;            // global dim

            float pp[NP];
            #pragma unroll
            for (int j = 0; j < NP; ++j)
                pp[j] = bf2f(sw[(q * 23 + j) * 18 + m]);

            const float xraw = xr[gl];

            // softmax WITHOUT max-subtraction: |P| is bounded (~O(1)) by the
            // 0.05-scaled network, far from exp overflow; ratio is identical.
            float ew[KN], eh[KN];
            #pragma unroll
            for (int j = 0; j < KN; ++j) {
                ew[j] = __expf(pp[j]);
                eh[j] = __expf(pp[8 + j]);
            }
            const float sw_ = ((ew[0] + ew[1]) + (ew[2] + ew[3]))
                            + ((ew[4] + ew[5]) + (ew[6] + ew[7]));
            const float sh_ = ((eh[0] + eh[1]) + (eh[2] + eh[3]))
                            + ((eh[4] + eh[5]) + (eh[6] + eh[7]));
            const float cmul = 8.0f / 1.01f;     // 2*Bi/(1+ADJ)
            const float cadd = 0.00125f * (8.0f / 1.01f);
            const float rw = cmul / sw_, rh = cmul / sh_;
            float width[KN], height[KN];
            #pragma unroll
            for (int j = 0; j < KN; ++j) {
                width[j]  = fmaf(ew[j], rw, cadd);
                height[j] = fmaf(eh[j], rh, cadd);
            }
            float dv[KN + 1];
            dv[0] = 1.0f; dv[KN] = 1.0f;
            #pragma unroll
            for (int i = 1; i < KN; ++i) dv[i] = softplusf(pp[15 + i]) + 0.001f;

            const bool inside = (xraw > -BI_F) && (xraw < BI_F);
            const float xcl = fminf(fmaxf(xraw, -BI_F), BI_F);

            float cx = -BI_F, cy = -BI_F;
            float xk = -BI_F, yk = -BI_F, xk1 = 0.f, yk1 = 0.f, dk = 1.f, dk1 = 1.f;
            #pragma unroll
            for (int i = 0; i < KN; ++i) {
                const float nx = cx + width[i];
                const float ny = cy + height[i];
                const bool cc = (xcl >= cx);
                xk  = cc ? cx : xk;    yk  = cc ? cy : yk;
                xk1 = cc ? nx : xk1;   yk1 = cc ? ny : yk1;
                dk  = cc ? dv[i] : dk; dk1 = cc ? dv[i + 1] : dk1;
                cx = nx; cy = ny;
            }

            const float invw = 1.0f / (xk1 - xk);
            const float sk   = (yk1 - yk) * invw;
            const float xi   = (xcl - xk) * invw;
            const float omx  = 1.0f - xi;
            const float den  = sk + (dk1 + dk - 2.0f * sk) * xi * omx;
            const float rden = 1.0f / den;
            float outv = fmaf((yk1 - yk) * (sk * xi * xi + dk * xi * omx), rden, yk);
            const float numl = dk1 * xi * xi + 2.0f * sk * xi * omx + dk * omx * omx;
            // 2log(sk) + log(numl) - 2log(den) == log(sk^2 * numl * rden^2)
            float ldj = __logf(sk * sk * numl * rden * rden);
            outv = inside ? outv : xraw;
            ldj  = inside ? ldj : 0.0f;

            xout[(size_t)(r0 + m) * DIMS + (DIMS - 1 - d)] = outv;
            ldsum += ldj;
        }

        if (gl < NGRPB - 1) {
            __syncthreads();         // B2: drains DMA (vmcnt) for all waves
        }
    }

    // ---- ld reduce across the 4 lanes sharing each b (q=0..3), then one
    //      atomicAdd per (row, flow, dhalf) into the zero-initialized output.
    float v = ldsum + __shfl_xor(ldsum, 16, 64);
    v = v + __shfl_xor(v, 32, 64);
    if (ln < 16) {
        atomicAdd(ldp + (r0 + ln), v);
    }
}

// ---------------------------------------------------------------------------
extern "C" void kernel_launch(void* const* d_in, const int* in_sizes, int n_in,
                              void* d_out, int out_size, void* d_ws, size_t ws_size,
                              hipStream_t stream)
{
    const float* x      = (const float*)d_in[0];
    const float* y      = (const float*)d_in[1];
    const float* f_W1   = (const float*)d_in[2];
    const float* f_b1   = (const float*)d_in[3];
    const float* f_Wout = (const float*)d_in[4];
    const float* f_bout = (const float*)d_in[5];
    const float* g_W1   = (const float*)d_in[6];
    const float* g_b1   = (const float*)d_in[7];
    const float* g_Wout = (const float*)d_in[8];
    const float* g_bout = (const float*)d_in[9];

    float* out = (float*)d_out;
    float* xo  = out;                               // [B, D]
    float* ldf = out + (size_t)BATCH * DIMS;        // [B]
    float* yo  = ldf + BATCH;                       // [B, D]
    float* ldg = yo + (size_t)BATCH * DIMS;         // [B]

    // Workspace layout: identical footprint to the proven versions.
    unsigned short* womask = (unsigned short*)d_ws;           // 2*PF_WOUT bf16
    unsigned short* w1mask = womask + 2 * (size_t)PF_WOUT;    // 2*PF_W1 bf16
    float* xA_f = (float*)(w1mask + 2 * (size_t)PF_W1);       // [B,D] ping (f)
    float* xA_g = xA_f + (size_t)BATCH * DIMS;                // [B,D] ping (g)

    premask_kernel<<<dim3(2048), dim3(256), 0, stream>>>(
        f_Wout, g_Wout, f_W1, g_W1, womask, w1mask, ldf, ldg);

    for (int l = 0; l < NLAYERS; ++l) {
        const float* inf = (l == 0) ? x : ((l & 1) ? xA_f : xo);
        const float* ing = (l == 0) ? y : ((l & 1) ? xA_g : yo);
        float* outf = (l & 1) ? xo : xA_f;
        float* outg = (l & 1) ? yo : xA_g;

        layer_kernel<<<dim3(BATCH / 64, 4), dim3(256), 0, stream>>>(
            inf, ing, outf, outg,
            w1mask + (size_t)l * WID * DIMS,
            w1mask + (size_t)PF_W1 + (size_t)l * WID * DIMS,
            f_b1 + (size_t)l * WID, g_b1 + (size_t)l * WID,
            womask + (size_t)l * NCOL * WID,
            womask + (size_t)PF_WOUT + (size_t)l * NCOL * WID,
            f_bout + (size_t)l * NCOL, g_bout + (size_t)l * NCOL,
            ldf, ldg);
    }
}

// Round 7
// 469.638 us; speedup vs baseline: 1.9242x; 1.0635x over previous
//
#include <hip/hip_runtime.h>
#include <math.h>

#define BATCH   16384
#define DIMS    64
#define WID     128
#define KN      8
#define NP      23        // 3*KN - 1
#define NCOL    (DIMS * NP)   // 1472 param columns
#define NLAYERS 8
#define BI_F    4.0f
#define GRP     92        // param cols per 4-dim group
#define NGRPB   8         // groups per block (dhalf split)
#define LOG2E   1.44269504f

#define PF_WOUT (NLAYERS * NCOL * WID)        // per-flow Wout elems: 1,507,328
#define PF_W1   (NLAYERS * WID * DIMS)        // per-flow W1 elems:   65,536

typedef short s16x8 __attribute__((ext_vector_type(8)));
typedef float f32x4 __attribute__((ext_vector_type(4)));

__device__ __forceinline__ unsigned short f2bf(float f) {
    unsigned int u = __builtin_bit_cast(unsigned int, f);
    unsigned int r = (u + 0x7FFFu + ((u >> 16) & 1u)) >> 16;
    return (unsigned short)r;
}
__device__ __forceinline__ float bf2f(unsigned short u) {
    return __builtin_bit_cast(float, (unsigned int)u << 16);
}

// global -> LDS direct DMA, 16B per lane. LDS dest is wave-uniform base +
// lane*16 (HW rule); global src is per-lane.
__device__ __forceinline__ void stage16(const unsigned short* g, unsigned short* l) {
    __builtin_amdgcn_global_load_lds(
        (__attribute__((address_space(1))) void*)g,
        (__attribute__((address_space(3))) void*)l,
        16, 0, 0);
}

// ---------------------------------------------------------------------------
// Pre-mask MADE weights -> bf16 workspace. womask is stored K-SWIZZLED within
// each 128-short column: k -> k ^ ((col&7)<<4). The linear global_load_lds
// then lands the swizzled layout in LDS, and the ds_read_b128 B-fragment
// reads (which XOR the same key) are conflict-light. Swizzle keeps 8-short
// runs contiguous (key has no bits <4), so fragment order is intact.
// NEW: womask values are PRE-SCALED by log2e. Every P param col is consumed
// exclusively through exp (cols j<16: softmax exp; j>=16: softplus exp), so
// P' = P*log2e lets the spline use exp2f(pp) with no multiply — identical
// math to __expf's internal x*log2e prescale. W1 is NOT scaled (feeds H).
// Also zero-inits ldf/ldg (atomicAdd targets; harness poisons out buffer).
// ---------------------------------------------------------------------------
__global__ __launch_bounds__(256) void premask_kernel(
    const float* __restrict__ f_wout, const float* __restrict__ g_wout,
    const float* __restrict__ f_w1,   const float* __restrict__ g_w1,
    unsigned short* __restrict__ womask, unsigned short* __restrict__ w1mask,
    float* __restrict__ ldf, float* __restrict__ ldg)
{
    const int idx    = blockIdx.x * 256 + threadIdx.x;
    const int stride = gridDim.x * 256;

    const int totw = 2 * PF_WOUT;
    for (int i = idx; i < totw; i += stride) {
        int fl = i / PF_WOUT;
        int r  = i % PF_WOUT;
        int h  = r % WID;
        int o  = (r / WID) % NCOL;              // layer-local param col
        int d  = o / NP;
        int hd = h % (DIMS - 1) + 1;            // hid_deg
        const float* src = fl ? g_wout : f_wout;
        unsigned short v = (hd <= d) ? f2bf(src[r] * LOG2E) : (unsigned short)0;
        const int dst = i - h + (h ^ ((o & 7) << 4));   // swizzled k position
        womask[dst] = v;
    }

    const int tot1 = 2 * PF_W1;
    for (int i = idx; i < tot1; i += stride) {
        int fl = i / PF_W1;
        int r  = i % PF_W1;
        int c  = r % DIMS;
        int w  = (r / DIMS) % WID;
        int deg = w % (DIMS - 1) + 1;           // hid_deg
        const float* src = fl ? g_w1 : f_w1;
        w1mask[i] = (c < deg) ? f2bf(src[r]) : (unsigned short)0;
    }

    for (int i = idx; i < BATCH; i += stride) {
        ldf[i] = 0.0f;
        ldg[i] = 0.0f;
    }
}

// ---------------------------------------------------------------------------
// One MAF layer. Grid (BATCH/64, 4): blockIdx.y = flow + 2*dhalf. Block = 4
// waves, 64 batch rows, 32 dims (8 groups of 4). LDS = 40,960 B (R5-proven
// geometry; Hs pitch MUST be >=128 — round 6's pitch-120 overlapped H rows).
//
// Wl is SINGLE-buffered (92 cols x 128 k = 23,552 B): per group,
//   MFMA(g) -> B1(all reads done) -> issue DMA(g+1)+prefetch bias/x ->
//   spline(g) hides the DMA latency -> B2 (drains vmcnt) -> next group.
// S overlays Hs (GEMM1 H-tile, dead after af-frag loads) and Pc (P staging)
// as same-type u16 views of one array (compiler-visible aliasing).
// ---------------------------------------------------------------------------
__global__ __launch_bounds__(256, 4) void layer_kernel(
    const float* __restrict__ xin_f, const float* __restrict__ xin_g,
    float* __restrict__ xout_f,      float* __restrict__ xout_g,
    const unsigned short* __restrict__ w1m_f, const unsigned short* __restrict__ w1m_g,
    const float* __restrict__ b1_f,  const float* __restrict__ b1_g,
    const unsigned short* __restrict__ wom_f, const unsigned short* __restrict__ wom_g,
    const float* __restrict__ bo_f,  const float* __restrict__ bo_g,
    float* __restrict__ ld_f,        float* __restrict__ ld_g)
{
    // Wl: staged weight tile, linear [92 cols][128 k] (k pre-swizzled
    //     by ((global_col)&7)<<4, baked into womask).          23,552 B
    __shared__ __align__(16) unsigned short Wl[GRP * WID];
    // S: per-wave overlay, 2176 shorts. Hs view: [16 rows][136] (272B rows,
    //    b128-aligned, 34-dword pitch spreads banks). Pc view: col-major
    //    [96 cols][18] (1728 <= 2176). Hs dead before first Pc write.
    __shared__ __align__(16) unsigned short S[4][2176];
    // total 40,960 B

    const int t     = threadIdx.x;
    const int wv    = t >> 6;          // wave 0..3
    const int ln    = t & 63;
    const int m     = ln & 15;         // row-in-tile / col-in-tile index
    const int q     = ln >> 4;         // quad
    const int flow  = blockIdx.y & 1;
    const int dhalf = blockIdx.y >> 1; // dim half: groups [dhalf*8, dhalf*8+8)
    const int g0    = dhalf * NGRPB;
    const int r0    = blockIdx.x * 64 + wv * 16;   // this wave's first batch row

    const float* xin          = flow ? xin_g : xin_f;
    float*       xout         = flow ? xout_g : xout_f;
    const unsigned short* w1m = flow ? w1m_g : w1m_f;
    const float* b1           = flow ? b1_g  : b1_f;
    const unsigned short* wom = flow ? wom_g : wom_f;
    const float* bo           = flow ? bo_g  : bo_f;
    float*       ldp          = flow ? ld_g  : ld_f;

    // ---- prologue: DMA-stage group g0's 92-col slab (23 chunks of 1KB;
    //      wave wv takes chunks wv, wv+4, ...). Fire-and-forget; drained by
    //      the pre-loop barrier, hidden under GEMM1.
    {
        const unsigned short* src = wom + (size_t)g0 * GRP * WID + ln * 8;
        #pragma unroll
        for (int i = 0; i < 6; ++i) {
            const int c = wv + 4 * i;
            if (c < 23) stage16(src + c * 512, Wl + c * 512);
        }
    }

    // ---- GEMM1: A-frags from x (global, fp32 -> bf16) ----
    const float* xrow = xin + (size_t)(r0 + m) * DIMS;
    s16x8 xa[2];
    #pragma unroll
    for (int ks = 0; ks < 2; ++ks) {
        float4 v0 = *(const float4*)(xrow + ks * 32 + q * 8);
        float4 v1 = *(const float4*)(xrow + ks * 32 + q * 8 + 4);
        s16x8 a;
        a[0] = (short)f2bf(v0.x); a[1] = (short)f2bf(v0.y);
        a[2] = (short)f2bf(v0.z); a[3] = (short)f2bf(v0.w);
        a[4] = (short)f2bf(v1.x); a[5] = (short)f2bf(v1.y);
        a[6] = (short)f2bf(v1.z); a[7] = (short)f2bf(v1.w);
        xa[ks] = a;
    }

    f32x4 hacc[8];
    #pragma unroll
    for (int nt = 0; nt < 8; ++nt) {
        float bv = b1[nt * 16 + m];
        hacc[nt] = (f32x4){bv, bv, bv, bv};
    }
    #pragma unroll
    for (int ks = 0; ks < 2; ++ks) {
        #pragma unroll
        for (int nt = 0; nt < 8; ++nt) {
            s16x8 bfr = *(const s16x8*)(w1m + (nt * 16 + m) * DIMS + ks * 32 + q * 8);
            hacc[nt] = __builtin_amdgcn_mfma_f32_16x16x32_bf16(xa[ks], bfr, hacc[nt], 0, 0, 0);
        }
    }
    // ReLU -> bf16 -> Hs view of S. Lane holds col (h = nt*16+m), rows q*4+rr.
    unsigned short* sw = &S[wv][0];
    #pragma unroll
    for (int nt = 0; nt < 8; ++nt) {
        #pragma unroll
        for (int rr = 0; rr < 4; ++rr) {
            sw[(q * 4 + rr) * 136 + nt * 16 + m] = f2bf(fmaxf(hacc[nt][rr], 0.0f));
        }
    }
    asm volatile("" ::: "memory");   // pin Hs stores before af loads

    // ---- A-frags for GEMM2 from Hs (b128 reads, wave-private) ----
    s16x8 af[4];
    #pragma unroll
    for (int ks = 0; ks < 4; ++ks)
        af[ks] = *(const s16x8*)&sw[m * 136 + ks * 32 + q * 8];
    asm volatile("" ::: "memory");   // af read before Pc overwrites Hs

    // ---- bias + x prefetch for group g0 (bias scaled by log2e to match
    //      the pre-scaled womask) ----
    float bnx[6];
    #pragma unroll
    for (int nt = 0; nt < 6; ++nt) {
        int o = g0 * GRP + nt * 16 + m;
        o = (o < NCOL) ? o : (NCOL - 1);
        bnx[nt] = bo[o] * LOG2E;
    }
    float xcur = xin[(size_t)(r0 + m) * DIMS + g0 * 4 + q];
    float xnxt = 0.0f;

    float ldsum = 0.0f;

    __syncthreads();                 // group-g0 weights resident for all waves

    #pragma unroll 1
    for (int gl = 0; gl < NGRPB; ++gl) {
        const int gg = g0 + gl;      // global 4-dim group

        // ---- GEMM2 group gg from LDS (swizzled): cols [92gg, 92gg+96) ----
        f32x4 acc[6];
        #pragma unroll
        for (int nt = 0; nt < 6; ++nt)
            acc[nt] = (f32x4){bnx[nt], bnx[nt], bnx[nt], bnx[nt]};

        const int swz = ((gg * 4 + m) & 7) << 4;  // (92gg+nt*16+m)&7 == (4gg+m)&7
        #pragma unroll
        for (int ks = 0; ks < 4; ++ks) {
            #pragma unroll
            for (int nt = 0; nt < 6; ++nt) {
                const s16x8 bfr = *(const s16x8*)&Wl[
                    (nt * 16 + m) * WID + ((ks * 32 + q * 8) ^ swz)];
                acc[nt] = __builtin_amdgcn_mfma_f32_16x16x32_bf16(af[ks], bfr, acc[nt], 0, 0, 0);
            }
        }

        if (gl < NGRPB - 1) {
            __syncthreads();         // B1: all waves done reading Wl(gg)
            // ---- issue DMA for group gg+1 into the same buffer; latency
            //      hides under the spline below; drained at B2. Also
            //      prefetch next group's bias and x (register scalars —
            //      runtime-indexed arrays here go to scratch, rule #20).
            const unsigned short* src = wom + (size_t)(gg + 1) * GRP * WID + ln * 8;
            #pragma unroll
            for (int i = 0; i < 6; ++i) {
                const int c = wv + 4 * i;
                if (c < 23) stage16(src + c * 512, Wl + c * 512);
            }
            #pragma unroll
            for (int nt = 0; nt < 6; ++nt) {
                int o = (gg + 1) * GRP + nt * 16 + m;
                o = (o < NCOL) ? o : (NCOL - 1);
                bnx[nt] = bo[o] * LOG2E;
            }
            xnxt = xin[(size_t)(r0 + m) * DIMS + (gg + 1) * 4 + q];
        }

        // P -> Pc view of S, col-major (pitch 18): lane col u = nt*16+m,
        // rows q*4..q*4+3 (RNE bf16; consecutive rr merge to wider stores).
        #pragma unroll
        for (int nt = 0; nt < 6; ++nt) {
            const int c18 = (nt * 16 + m) * 18 + q * 4;
            #pragma unroll
            for (int rr = 0; rr < 4; ++rr)
                sw[c18 + rr] = f2bf(acc[nt][rr]);
        }

        // ---- spline: 4 dims x 16 rows, lane = (b=m, dim-in-group=q).
        //      pp is pre-scaled by log2e: exp2f(pp) == e^{P_raw}. ----
        {
            const int d = gg * 4 + q;            // global dim

            float pp[NP];
            #pragma unroll
            for (int j = 0; j < NP; ++j)
                pp[j] = bf2f(sw[(q * 23 + j) * 18 + m]);

            const float xraw = xcur;

            // softmax WITHOUT max-subtraction: |P| is bounded (~O(1)) by the
            // 0.05-scaled network, far from exp overflow; ratio is identical.
            float ew[KN], eh[KN];
            #pragma unroll
            for (int j = 0; j < KN; ++j) {
                ew[j] = exp2f(pp[j]);
                eh[j] = exp2f(pp[8 + j]);
            }
            const float sw_ = ((ew[0] + ew[1]) + (ew[2] + ew[3]))
                            + ((ew[4] + ew[5]) + (ew[6] + ew[7]));
            const float sh_ = ((eh[0] + eh[1]) + (eh[2] + eh[3]))
                            + ((eh[4] + eh[5]) + (eh[6] + eh[7]));
            const float cmul = 8.0f / 1.01f;     // 2*Bi/(1+ADJ)
            const float cadd = 0.00125f * (8.0f / 1.01f);
            const float rw = cmul / sw_, rh = cmul / sh_;
            float width[KN], height[KN];
            #pragma unroll
            for (int j = 0; j < KN; ++j) {
                width[j]  = fmaf(ew[j], rw, cadd);
                height[j] = fmaf(eh[j], rh, cadd);
            }
            // softplus(p)+0.001 = ln2*log2(1 + 2^(p*log2e)) + 0.001; the
            // log2e prescale is baked into pp.
            float dv[KN + 1];
            dv[0] = 1.0f; dv[KN] = 1.0f;
            #pragma unroll
            for (int i = 1; i < KN; ++i) {
                const float tt = exp2f(pp[15 + i]);
                dv[i] = fmaf(__log2f(1.0f + tt), 0.69314718f, 0.001f);
            }

            const bool inside = (xraw > -BI_F) && (xraw < BI_F);
            const float xcl = fminf(fmaxf(xraw, -BI_F), BI_F);

            float cx = -BI_F, cy = -BI_F;
            float xk = -BI_F, yk = -BI_F, xk1 = 0.f, yk1 = 0.f, dk = 1.f, dk1 = 1.f;
            #pragma unroll
            for (int i = 0; i < KN; ++i) {
                const float nx = cx + width[i];
                const float ny = cy + height[i];
                const bool cc = (xcl >= cx);
                xk  = cc ? cx : xk;    yk  = cc ? cy : yk;
                xk1 = cc ? nx : xk1;   yk1 = cc ? ny : yk1;
                dk  = cc ? dv[i] : dk; dk1 = cc ? dv[i + 1] : dk1;
                cx = nx; cy = ny;
            }

            const float invw = 1.0f / (xk1 - xk);
            const float sk   = (yk1 - yk) * invw;
            const float xi   = (xcl - xk) * invw;
            const float omx  = 1.0f - xi;
            const float den  = sk + (dk1 + dk - 2.0f * sk) * xi * omx;
            const float rden = 1.0f / den;
            float outv = fmaf((yk1 - yk) * (sk * xi * xi + dk * xi * omx), rden, yk);
            const float numl = dk1 * xi * xi + 2.0f * sk * xi * omx + dk * omx * omx;
            // 2log(sk) + log(numl) - 2log(den) == log(sk^2 * numl * rden^2)
            float ldj = __logf(sk * sk * numl * rden * rden);
            outv = inside ? outv : xraw;
            ldj  = inside ? ldj : 0.0f;

            xout[(size_t)(r0 + m) * DIMS + (DIMS - 1 - d)] = outv;
            ldsum += ldj;
        }

        if (gl < NGRPB - 1) {
            __syncthreads();         // B2: drains DMA (vmcnt) for all waves
            xcur = xnxt;
        }
    }

    // ---- ld reduce across the 4 lanes sharing each b (q=0..3), then one
    //      atomicAdd per (row, flow, dhalf) into the zero-initialized output.
    float v = ldsum + __shfl_xor(ldsum, 16, 64);
    v = v + __shfl_xor(v, 32, 64);
    if (ln < 16) {
        atomicAdd(ldp + (r0 + ln), v);
    }
}

// ---------------------------------------------------------------------------
extern "C" void kernel_launch(void* const* d_in, const int* in_sizes, int n_in,
                              void* d_out, int out_size, void* d_ws, size_t ws_size,
                              hipStream_t stream)
{
    const float* x      = (const float*)d_in[0];
    const float* y      = (const float*)d_in[1];
    const float* f_W1   = (const float*)d_in[2];
    const float* f_b1   = (const float*)d_in[3];
    const float* f_Wout = (const float*)d_in[4];
    const float* f_bout = (const float*)d_in[5];
    const float* g_W1   = (const float*)d_in[6];
    const float* g_b1   = (const float*)d_in[7];
    const float* g_Wout = (const float*)d_in[8];
    const float* g_bout = (const float*)d_in[9];

    float* out = (float*)d_out;
    float* xo  = out;                               // [B, D]
    float* ldf = out + (size_t)BATCH * DIMS;        // [B]
    float* yo  = ldf + BATCH;                       // [B, D]
    float* ldg = yo + (size_t)BATCH * DIMS;         // [B]

    // Workspace layout: identical footprint to the proven versions.
    unsigned short* womask = (unsigned short*)d_ws;           // 2*PF_WOUT bf16
    unsigned short* w1mask = womask + 2 * (size_t)PF_WOUT;    // 2*PF_W1 bf16
    float* xA_f = (float*)(w1mask + 2 * (size_t)PF_W1);       // [B,D] ping (f)
    float* xA_g = xA_f + (size_t)BATCH * DIMS;                // [B,D] ping (g)

    premask_kernel<<<dim3(2048), dim3(256), 0, stream>>>(
        f_Wout, g_Wout, f_W1, g_W1, womask, w1mask, ldf, ldg);

    for (int l = 0; l < NLAYERS; ++l) {
        const float* inf = (l == 0) ? x : ((l & 1) ? xA_f : xo);
        const float* ing = (l == 0) ? y : ((l & 1) ? xA_g : yo);
        float* outf = (l & 1) ? xo : xA_f;
        float* outg = (l & 1) ? yo : xA_g;

        layer_kernel<<<dim3(BATCH / 64, 4), dim3(256), 0, stream>>>(
            inf, ing, outf, outg,
            w1mask + (size_t)l * WID * DIMS,
            w1mask + (size_t)PF_W1 + (size_t)l * WID * DIMS,
            f_b1 + (size_t)l * WID, g_b1 + (size_t)l * WID,
            womask + (size_t)l * NCOL * WID,
            womask + (size_t)PF_WOUT + (size_t)l * NCOL * WID,
            f_bout + (size_t)l * NCOL, g_bout + (size_t)l * NCOL,
            ldf, ldg);
    }
}

// Round 8
// 469.274 us; speedup vs baseline: 1.9256x; 1.0008x over previous
//
#include <hip/hip_runtime.h>
#include <math.h>

#define BATCH   16384
#define DIMS    64
#define WID     128
#define KN      8
#define NP      23        // 3*KN - 1
#define NCOL    (DIMS * NP)   // 1472 param columns
#define NLAYERS 8
#define BI_F    4.0f
#define GRP     92        // param cols per 4-dim group
#define NGRPB   8         // groups per block (dhalf split)
#define LOG2E   1.44269504f

#define PF_WOUT (NLAYERS * NCOL * WID)        // per-flow Wout elems: 1,507,328
#define PF_W1   (NLAYERS * WID * DIMS)        // per-flow W1 elems:   65,536

typedef short s16x8 __attribute__((ext_vector_type(8)));
typedef float f32x4 __attribute__((ext_vector_type(4)));

__device__ __forceinline__ unsigned short f2bf(float f) {
    unsigned int u = __builtin_bit_cast(unsigned int, f);
    unsigned int r = (u + 0x7FFFu + ((u >> 16) & 1u)) >> 16;
    return (unsigned short)r;
}
__device__ __forceinline__ float bf2f(unsigned short u) {
    return __builtin_bit_cast(float, (unsigned int)u << 16);
}

// global -> LDS direct DMA, 16B per lane. LDS dest is wave-uniform base +
// lane*16 (HW rule); global src is per-lane.
__device__ __forceinline__ void stage16(const unsigned short* g, unsigned short* l) {
    __builtin_amdgcn_global_load_lds(
        (__attribute__((address_space(1))) void*)g,
        (__attribute__((address_space(3))) void*)l,
        16, 0, 0);
}

// ---------------------------------------------------------------------------
// Pre-mask MADE weights -> bf16 workspace. womask is stored K-SWIZZLED within
// each 128-short column: k -> k ^ ((col&7)<<4). The linear global_load_lds
// then lands the swizzled layout in LDS, and the ds_read_b128 B-fragment
// reads (which XOR the same key) are conflict-light. Swizzle keeps 8-short
// runs contiguous (key has no bits <4), so fragment order is intact.
// womask values are PRE-SCALED by log2e (every P param col is consumed
// exclusively through exp/softplus-exp), so the spline uses exp2f(pp) with
// no multiply. W1 is NOT scaled (feeds H).
// Also zero-inits ldf/ldg (atomicAdd targets; harness poisons out buffer).
// ---------------------------------------------------------------------------
__global__ __launch_bounds__(256) void premask_kernel(
    const float* __restrict__ f_wout, const float* __restrict__ g_wout,
    const float* __restrict__ f_w1,   const float* __restrict__ g_w1,
    unsigned short* __restrict__ womask, unsigned short* __restrict__ w1mask,
    float* __restrict__ ldf, float* __restrict__ ldg)
{
    const int idx    = blockIdx.x * 256 + threadIdx.x;
    const int stride = gridDim.x * 256;

    const int totw = 2 * PF_WOUT;
    for (int i = idx; i < totw; i += stride) {
        int fl = i / PF_WOUT;
        int r  = i % PF_WOUT;
        int h  = r % WID;
        int o  = (r / WID) % NCOL;              // layer-local param col
        int d  = o / NP;
        int hd = h % (DIMS - 1) + 1;            // hid_deg
        const float* src = fl ? g_wout : f_wout;
        unsigned short v = (hd <= d) ? f2bf(src[r] * LOG2E) : (unsigned short)0;
        const int dst = i - h + (h ^ ((o & 7) << 4));   // swizzled k position
        womask[dst] = v;
    }

    const int tot1 = 2 * PF_W1;
    for (int i = idx; i < tot1; i += stride) {
        int fl = i / PF_W1;
        int r  = i % PF_W1;
        int c  = r % DIMS;
        int w  = (r / DIMS) % WID;
        int deg = w % (DIMS - 1) + 1;           // hid_deg
        const float* src = fl ? g_w1 : f_w1;
        w1mask[i] = (c < deg) ? f2bf(src[r]) : (unsigned short)0;
    }

    for (int i = idx; i < BATCH; i += stride) {
        ldf[i] = 0.0f;
        ldg[i] = 0.0f;
    }
}

// ---------------------------------------------------------------------------
// One MAF layer. Grid (BATCH/64, 4): blockIdx.y = flow + 2*dhalf. Block = 4
// waves, 64 batch rows, 32 dims (8 groups of 4). LDS = 40,960 B -> 4
// blocks/CU = 4 waves/SIMD max.
//
// ROUND 8: amdgpu_waves_per_eu(4,4) pins the register allocator at the
// 4-waves/SIMD occupancy that LDS already caps us to. Round 5/7 measured
// VGPR_Count=64 (the 8-wave boundary) — the allocator targeted an occupancy
// LDS makes impossible and paid for it with LDS-remat/recompute of the
// spline state (~2x VALU inflation; dur pinned at ~59us across 3 structural
// variants). Budget 128 fits the measured ~100-110 peak liveness.
//
// Wl is SINGLE-buffered (92 cols x 128 k = 23,552 B): per group,
//   MFMA(g) -> B1(all reads done) -> issue DMA(g+1)+prefetch bias/x ->
//   spline(g) hides the DMA latency -> B2 (drains vmcnt) -> next group.
// S overlays Hs (GEMM1 H-tile, dead after af-frag loads) and Pc (P staging)
// as same-type u16 views of one array (compiler-visible aliasing).
// Hs pitch MUST be >=128 (round-6's 120 overlapped H rows).
// ---------------------------------------------------------------------------
__global__ __launch_bounds__(256)
__attribute__((amdgpu_waves_per_eu(4, 4)))
void layer_kernel(
    const float* __restrict__ xin_f, const float* __restrict__ xin_g,
    float* __restrict__ xout_f,      float* __restrict__ xout_g,
    const unsigned short* __restrict__ w1m_f, const unsigned short* __restrict__ w1m_g,
    const float* __restrict__ b1_f,  const float* __restrict__ b1_g,
    const unsigned short* __restrict__ wom_f, const unsigned short* __restrict__ wom_g,
    const float* __restrict__ bo_f,  const float* __restrict__ bo_g,
    float* __restrict__ ld_f,        float* __restrict__ ld_g)
{
    // Wl: staged weight tile, linear [92 cols][128 k] (k pre-swizzled
    //     by ((global_col)&7)<<4, baked into womask).          23,552 B
    __shared__ __align__(16) unsigned short Wl[GRP * WID];
    // S: per-wave overlay, 2176 shorts. Hs view: [16 rows][136] (272B rows,
    //    b128-aligned, 34-dword pitch spreads banks). Pc view: col-major
    //    [96 cols][18] (1728 <= 2176). Hs dead before first Pc write.
    __shared__ __align__(16) unsigned short S[4][2176];
    // total 40,960 B

    const int t     = threadIdx.x;
    const int wv    = t >> 6;          // wave 0..3
    const int ln    = t & 63;
    const int m     = ln & 15;         // row-in-tile / col-in-tile index
    const int q     = ln >> 4;         // quad
    const int flow  = blockIdx.y & 1;
    const int dhalf = blockIdx.y >> 1; // dim half: groups [dhalf*8, dhalf*8+8)
    const int g0    = dhalf * NGRPB;
    const int r0    = blockIdx.x * 64 + wv * 16;   // this wave's first batch row

    const float* xin          = flow ? xin_g : xin_f;
    float*       xout         = flow ? xout_g : xout_f;
    const unsigned short* w1m = flow ? w1m_g : w1m_f;
    const float* b1           = flow ? b1_g  : b1_f;
    const unsigned short* wom = flow ? wom_g : wom_f;
    const float* bo           = flow ? bo_g  : bo_f;
    float*       ldp          = flow ? ld_g  : ld_f;

    // ---- prologue: DMA-stage group g0's 92-col slab (23 chunks of 1KB;
    //      wave wv takes chunks wv, wv+4, ...). Fire-and-forget; drained by
    //      the pre-loop barrier, hidden under GEMM1.
    {
        const unsigned short* src = wom + (size_t)g0 * GRP * WID + ln * 8;
        #pragma unroll
        for (int i = 0; i < 6; ++i) {
            const int c = wv + 4 * i;
            if (c < 23) stage16(src + c * 512, Wl + c * 512);
        }
    }

    // ---- GEMM1: A-frags from x (global, fp32 -> bf16) ----
    const float* xrow = xin + (size_t)(r0 + m) * DIMS;
    s16x8 xa[2];
    #pragma unroll
    for (int ks = 0; ks < 2; ++ks) {
        float4 v0 = *(const float4*)(xrow + ks * 32 + q * 8);
        float4 v1 = *(const float4*)(xrow + ks * 32 + q * 8 + 4);
        s16x8 a;
        a[0] = (short)f2bf(v0.x); a[1] = (short)f2bf(v0.y);
        a[2] = (short)f2bf(v0.z); a[3] = (short)f2bf(v0.w);
        a[4] = (short)f2bf(v1.x); a[5] = (short)f2bf(v1.y);
        a[6] = (short)f2bf(v1.z); a[7] = (short)f2bf(v1.w);
        xa[ks] = a;
    }

    f32x4 hacc[8];
    #pragma unroll
    for (int nt = 0; nt < 8; ++nt) {
        float bv = b1[nt * 16 + m];
        hacc[nt] = (f32x4){bv, bv, bv, bv};
    }
    #pragma unroll
    for (int ks = 0; ks < 2; ++ks) {
        #pragma unroll
        for (int nt = 0; nt < 8; ++nt) {
            s16x8 bfr = *(const s16x8*)(w1m + (nt * 16 + m) * DIMS + ks * 32 + q * 8);
            hacc[nt] = __builtin_amdgcn_mfma_f32_16x16x32_bf16(xa[ks], bfr, hacc[nt], 0, 0, 0);
        }
    }
    // ReLU -> bf16 -> Hs view of S. Lane holds col (h = nt*16+m), rows q*4+rr.
    unsigned short* sw = &S[wv][0];
    #pragma unroll
    for (int nt = 0; nt < 8; ++nt) {
        #pragma unroll
        for (int rr = 0; rr < 4; ++rr) {
            sw[(q * 4 + rr) * 136 + nt * 16 + m] = f2bf(fmaxf(hacc[nt][rr], 0.0f));
        }
    }
    asm volatile("" ::: "memory");   // pin Hs stores before af loads

    // ---- A-frags for GEMM2 from Hs (b128 reads, wave-private) ----
    s16x8 af[4];
    #pragma unroll
    for (int ks = 0; ks < 4; ++ks)
        af[ks] = *(const s16x8*)&sw[m * 136 + ks * 32 + q * 8];
    asm volatile("" ::: "memory");   // af read before Pc overwrites Hs

    // ---- bias + x prefetch for group g0 (bias scaled by log2e to match
    //      the pre-scaled womask) ----
    float bnx[6];
    #pragma unroll
    for (int nt = 0; nt < 6; ++nt) {
        int o = g0 * GRP + nt * 16 + m;
        o = (o < NCOL) ? o : (NCOL - 1);
        bnx[nt] = bo[o] * LOG2E;
    }
    float xcur = xin[(size_t)(r0 + m) * DIMS + g0 * 4 + q];
    float xnxt = 0.0f;

    float ldsum = 0.0f;

    __syncthreads();                 // group-g0 weights resident for all waves

    #pragma unroll 1
    for (int gl = 0; gl < NGRPB; ++gl) {
        const int gg = g0 + gl;      // global 4-dim group

        // ---- GEMM2 group gg from LDS (swizzled): cols [92gg, 92gg+96) ----
        f32x4 acc[6];
        #pragma unroll
        for (int nt = 0; nt < 6; ++nt)
            acc[nt] = (f32x4){bnx[nt], bnx[nt], bnx[nt], bnx[nt]};

        const int swz = ((gg * 4 + m) & 7) << 4;  // (92gg+nt*16+m)&7 == (4gg+m)&7
        #pragma unroll
        for (int ks = 0; ks < 4; ++ks) {
            #pragma unroll
            for (int nt = 0; nt < 6; ++nt) {
                const s16x8 bfr = *(const s16x8*)&Wl[
                    (nt * 16 + m) * WID + ((ks * 32 + q * 8) ^ swz)];
                acc[nt] = __builtin_amdgcn_mfma_f32_16x16x32_bf16(af[ks], bfr, acc[nt], 0, 0, 0);
            }
        }

        if (gl < NGRPB - 1) {
            __syncthreads();         // B1: all waves done reading Wl(gg)
            // ---- issue DMA for group gg+1 into the same buffer; latency
            //      hides under the spline below; drained at B2. Also
            //      prefetch next group's bias and x (register scalars —
            //      runtime-indexed arrays here go to scratch, rule #20).
            const unsigned short* src = wom + (size_t)(gg + 1) * GRP * WID + ln * 8;
            #pragma unroll
            for (int i = 0; i < 6; ++i) {
                const int c = wv + 4 * i;
                if (c < 23) stage16(src + c * 512, Wl + c * 512);
            }
            #pragma unroll
            for (int nt = 0; nt < 6; ++nt) {
                int o = (gg + 1) * GRP + nt * 16 + m;
                o = (o < NCOL) ? o : (NCOL - 1);
                bnx[nt] = bo[o] * LOG2E;
            }
            xnxt = xin[(size_t)(r0 + m) * DIMS + (gg + 1) * 4 + q];
        }

        // P -> Pc view of S, col-major (pitch 18): lane col u = nt*16+m,
        // rows q*4..q*4+3 (RNE bf16; consecutive rr merge to wider stores).
        #pragma unroll
        for (int nt = 0; nt < 6; ++nt) {
            const int c18 = (nt * 16 + m) * 18 + q * 4;
            #pragma unroll
            for (int rr = 0; rr < 4; ++rr)
                sw[c18 + rr] = f2bf(acc[nt][rr]);
        }

        // ---- spline: 4 dims x 16 rows, lane = (b=m, dim-in-group=q).
        //      pp is pre-scaled by log2e: exp2f(pp) == e^{P_raw}. ----
        {
            const int d = gg * 4 + q;            // global dim

            float pp[NP];
            #pragma unroll
            for (int j = 0; j < NP; ++j)
                pp[j] = bf2f(sw[(q * 23 + j) * 18 + m]);

            const float xraw = xcur;

            // softmax WITHOUT max-subtraction: |P| is bounded (~O(1)) by the
            // 0.05-scaled network, far from exp overflow; ratio is identical.
            float ew[KN], eh[KN];
            #pragma unroll
            for (int j = 0; j < KN; ++j) {
                ew[j] = exp2f(pp[j]);
                eh[j] = exp2f(pp[8 + j]);
            }
            const float sw_ = ((ew[0] + ew[1]) + (ew[2] + ew[3]))
                            + ((ew[4] + ew[5]) + (ew[6] + ew[7]));
            const float sh_ = ((eh[0] + eh[1]) + (eh[2] + eh[3]))
                            + ((eh[4] + eh[5]) + (eh[6] + eh[7]));
            const float cmul = 8.0f / 1.01f;     // 2*Bi/(1+ADJ)
            const float cadd = 0.00125f * (8.0f / 1.01f);
            const float rw = cmul / sw_, rh = cmul / sh_;
            float width[KN], height[KN];
            #pragma unroll
            for (int j = 0; j < KN; ++j) {
                width[j]  = fmaf(ew[j], rw, cadd);
                height[j] = fmaf(eh[j], rh, cadd);
            }
            // softplus(p)+0.001 = ln2*log2(1 + 2^(p*log2e)) + 0.001; the
            // log2e prescale is baked into pp.
            float dv[KN + 1];
            dv[0] = 1.0f; dv[KN] = 1.0f;
            #pragma unroll
            for (int i = 1; i < KN; ++i) {
                const float tt = exp2f(pp[15 + i]);
                dv[i] = fmaf(__log2f(1.0f + tt), 0.69314718f, 0.001f);
            }

            const bool inside = (xraw > -BI_F) && (xraw < BI_F);
            const float xcl = fminf(fmaxf(xraw, -BI_F), BI_F);

            float cx = -BI_F, cy = -BI_F;
            float xk = -BI_F, yk = -BI_F, xk1 = 0.f, yk1 = 0.f, dk = 1.f, dk1 = 1.f;
            #pragma unroll
            for (int i = 0; i < KN; ++i) {
                const float nx = cx + width[i];
                const float ny = cy + height[i];
                const bool cc = (xcl >= cx);
                xk  = cc ? cx : xk;    yk  = cc ? cy : yk;
                xk1 = cc ? nx : xk1;   yk1 = cc ? ny : yk1;
                dk  = cc ? dv[i] : dk; dk1 = cc ? dv[i + 1] : dk1;
                cx = nx; cy = ny;
            }

            const float invw = 1.0f / (xk1 - xk);
            const float sk   = (yk1 - yk) * invw;
            const float xi   = (xcl - xk) * invw;
            const float omx  = 1.0f - xi;
            const float den  = sk + (dk1 + dk - 2.0f * sk) * xi * omx;
            const float rden = 1.0f / den;
            float outv = fmaf((yk1 - yk) * (sk * xi * xi + dk * xi * omx), rden, yk);
            const float numl = dk1 * xi * xi + 2.0f * sk * xi * omx + dk * omx * omx;
            // 2log(sk) + log(numl) - 2log(den) == log(sk^2 * numl * rden^2)
            float ldj = __logf(sk * sk * numl * rden * rden);
            outv = inside ? outv : xraw;
            ldj  = inside ? ldj : 0.0f;

            xout[(size_t)(r0 + m) * DIMS + (DIMS - 1 - d)] = outv;
            ldsum += ldj;
        }

        if (gl < NGRPB - 1) {
            __syncthreads();         // B2: drains DMA (vmcnt) for all waves
            xcur = xnxt;
        }
    }

    // ---- ld reduce across the 4 lanes sharing each b (q=0..3), then one
    //      atomicAdd per (row, flow, dhalf) into the zero-initialized output.
    float v = ldsum + __shfl_xor(ldsum, 16, 64);
    v = v + __shfl_xor(v, 32, 64);
    if (ln < 16) {
        atomicAdd(ldp + (r0 + ln), v);
    }
}

// ---------------------------------------------------------------------------
extern "C" void kernel_launch(void* const* d_in, const int* in_sizes, int n_in,
                              void* d_out, int out_size, void* d_ws, size_t ws_size,
                              hipStream_t stream)
{
    const float* x      = (const float*)d_in[0];
    const float* y      = (const float*)d_in[1];
    const float* f_W1   = (const float*)d_in[2];
    const float* f_b1   = (const float*)d_in[3];
    const float* f_Wout = (const float*)d_in[4];
    const float* f_bout = (const float*)d_in[5];
    const float* g_W1   = (const float*)d_in[6];
    const float* g_b1   = (const float*)d_in[7];
    const float* g_Wout = (const float*)d_in[8];
    const float* g_bout = (const float*)d_in[9];

    float* out = (float*)d_out;
    float* xo  = out;                               // [B, D]
    float* ldf = out + (size_t)BATCH * DIMS;        // [B]
    float* yo  = ldf + BATCH;                       // [B, D]
    float* ldg = yo + (size_t)BATCH * DIMS;         // [B]

    // Workspace layout: identical footprint to the proven versions.
    unsigned short* womask = (unsigned short*)d_ws;           // 2*PF_WOUT bf16
    unsigned short* w1mask = womask + 2 * (size_t)PF_WOUT;    // 2*PF_W1 bf16
    float* xA_f = (float*)(w1mask + 2 * (size_t)PF_W1);       // [B,D] ping (f)
    float* xA_g = xA_f + (size_t)BATCH * DIMS;                // [B,D] ping (g)

    premask_kernel<<<dim3(2048), dim3(256), 0, stream>>>(
        f_Wout, g_Wout, f_W1, g_W1, womask, w1mask, ldf, ldg);

    for (int l = 0; l < NLAYERS; ++l) {
        const float* inf = (l == 0) ? x : ((l & 1) ? xA_f : xo);
        const float* ing = (l == 0) ? y : ((l & 1) ? xA_g : yo);
        float* outf = (l & 1) ? xo : xA_f;
        float* outg = (l & 1) ? yo : xA_g;

        layer_kernel<<<dim3(BATCH / 64, 4), dim3(256), 0, stream>>>(
            inf, ing, outf, outg,
            w1mask + (size_t)l * WID * DIMS,
            w1mask + (size_t)PF_W1 + (size_t)l * WID * DIMS,
            f_b1 + (size_t)l * WID, g_b1 + (size_t)l * WID,
            womask + (size_t)l * NCOL * WID,
            womask + (size_t)PF_WOUT + (size_t)l * NCOL * WID,
            f_bout + (size_t)l * NCOL, g_bout + (size_t)l * NCOL,
            ldf, ldg);
    }
}

// Round 9
// 453.873 us; speedup vs baseline: 1.9910x; 1.0339x over previous
//
#include <hip/hip_runtime.h>
#include <math.h>

#define BATCH   16384
#define DIMS    64
#define WID     128
#define KN      8
#define NP      23        // 3*KN - 1
#define NCOL    (DIMS * NP)   // 1472 param columns
#define NLAYERS 8
#define BI_F    4.0f
#define GRP     92        // param cols per 4-dim group
#define NGRP    16        // groups per layer (full 64 dims per block)
#define XPITCH  68        // Xf row pitch in floats (68%32=4 -> 2-way free)
#define LOG2E   1.44269504f

#define PF_WOUT (NLAYERS * NCOL * WID)        // per-flow Wout elems: 1,507,328
#define PF_W1   (NLAYERS * WID * DIMS)        // per-flow W1 elems:   65,536

typedef short s16x8 __attribute__((ext_vector_type(8)));
typedef float f32x4 __attribute__((ext_vector_type(4)));

__device__ __forceinline__ unsigned short f2bf(float f) {
    unsigned int u = __builtin_bit_cast(unsigned int, f);
    unsigned int r = (u + 0x7FFFu + ((u >> 16) & 1u)) >> 16;
    return (unsigned short)r;
}
__device__ __forceinline__ float bf2f(unsigned short u) {
    return __builtin_bit_cast(float, (unsigned int)u << 16);
}

// global -> LDS direct DMA, 16B per lane. LDS dest is wave-uniform base +
// lane*16 (HW rule); global src is per-lane.
__device__ __forceinline__ void stage16(const unsigned short* g, unsigned short* l) {
    __builtin_amdgcn_global_load_lds(
        (__attribute__((address_space(1))) void*)g,
        (__attribute__((address_space(3))) void*)l,
        16, 0, 0);
}

// ---------------------------------------------------------------------------
// Pre-mask MADE weights -> bf16 workspace. womask is stored K-SWIZZLED within
// each 128-short column: k -> k ^ ((col&7)<<4); the linear global_load_lds
// lands the swizzled layout in LDS and the ds_read_b128 B-fragment reads XOR
// the same key (conflict-light, 8-short runs intact). womask PRE-SCALED by
// log2e (all P param cols are consumed through exp/softplus-exp only), so
// the spline uses exp2f with no multiply. W1 NOT scaled (feeds H).
// ---------------------------------------------------------------------------
__global__ __launch_bounds__(256) void premask_kernel(
    const float* __restrict__ f_wout, const float* __restrict__ g_wout,
    const float* __restrict__ f_w1,   const float* __restrict__ g_w1,
    unsigned short* __restrict__ womask, unsigned short* __restrict__ w1mask)
{
    const int idx    = blockIdx.x * 256 + threadIdx.x;
    const int stride = gridDim.x * 256;

    const int totw = 2 * PF_WOUT;
    for (int i = idx; i < totw; i += stride) {
        int fl = i / PF_WOUT;
        int r  = i % PF_WOUT;
        int h  = r % WID;
        int o  = (r / WID) % NCOL;              // layer-local param col
        int d  = o / NP;
        int hd = h % (DIMS - 1) + 1;            // hid_deg
        const float* src = fl ? g_wout : f_wout;
        unsigned short v = (hd <= d) ? f2bf(src[r] * LOG2E) : (unsigned short)0;
        const int dst = i - h + (h ^ ((o & 7) << 4));   // swizzled k position
        womask[dst] = v;
    }

    const int tot1 = 2 * PF_W1;
    for (int i = idx; i < tot1; i += stride) {
        int fl = i / PF_W1;
        int r  = i % PF_W1;
        int c  = r % DIMS;
        int w  = (r / DIMS) % WID;
        int deg = w % (DIMS - 1) + 1;           // hid_deg
        const float* src = fl ? g_w1 : f_w1;
        w1mask[i] = (c < deg) ? f2bf(src[r]) : (unsigned short)0;
    }
}

// ---------------------------------------------------------------------------
// FUSED 8-layer MAF kernel. Grid (BATCH/64, 2): blockIdx.y = flow. Block =
// 4 waves, 64 batch rows, ALL 64 dims, loops all 8 layers in-block:
//   - x lives in a double-buffered LDS ping-pong Xf[2] (f32, wave-private
//     rows -> no barriers for x; the per-layer flip is the write index).
//     Eliminates inter-layer global round-trips, the scattered per-group
//     global stores (which every B2 vmcnt(0)-drained), and 7 of 8 launches.
//   - flat 128-group schedule: the proven single-buffer Wl pipeline
//     {MFMA -> B1 -> DMA(next flat group)+bias prefetch -> Pc+spline -> B2}
//     crosses layer boundaries (next of (l,15) is (l+1,0)); GEMM1 of layer
//     l+1 slots between B2(l,15) and MFMA(l+1,0) touching only Xf/S.
//   - ld accumulates in-register across layers; ONE plain store per row at
//     the end (exclusive owner -> no atomics, no zero-init).
// LDS: Wl 23,552 + S 17,408 + Xf 34,816 = 75,776 B -> 2 blocks/CU; grid
// 512 = exactly 2/CU. Phase overlap comes from inter-block drift (blocks
// are fully independent now), not occupancy.
// ---------------------------------------------------------------------------
__global__ __launch_bounds__(256)
__attribute__((amdgpu_waves_per_eu(2, 2)))
void flow8_kernel(
    const float* __restrict__ xin_f, const float* __restrict__ xin_g,
    float* __restrict__ xout_f,      float* __restrict__ xout_g,
    const unsigned short* __restrict__ w1m_f, const unsigned short* __restrict__ w1m_g,
    const float* __restrict__ b1_f,  const float* __restrict__ b1_g,
    const unsigned short* __restrict__ wom_f, const unsigned short* __restrict__ wom_g,
    const float* __restrict__ bo_f,  const float* __restrict__ bo_g,
    float* __restrict__ ld_f,        float* __restrict__ ld_g)
{
    // Wl: staged weight tile, linear [92 cols][128 k] (k pre-swizzled).
    __shared__ __align__(16) unsigned short Wl[GRP * WID];        // 23,552 B
    // S: per-wave overlay. Hs view [16][136] u16; Pc view col-major [96][18].
    __shared__ __align__(16) unsigned short S[4][2176];           // 17,408 B
    // Xf: x ping-pong, per-wave 16 rows x 64 dims f32 (pitch 68: 2-way free).
    __shared__ __align__(16) float Xf[2][4][16][XPITCH];          // 34,816 B

    const int t    = threadIdx.x;
    const int wv   = t >> 6;          // wave 0..3
    const int ln   = t & 63;
    const int m    = ln & 15;         // row-in-tile / col-in-tile index
    const int q    = ln >> 4;         // quad
    const int flow = blockIdx.y;
    const int r0   = blockIdx.x * 64 + wv * 16;   // this wave's first batch row

    const float* xin          = flow ? xin_g : xin_f;
    float*       xout         = flow ? xout_g : xout_f;
    const unsigned short* w1m = flow ? w1m_g : w1m_f;
    const float* b1           = flow ? b1_g  : b1_f;
    const unsigned short* wom = flow ? wom_g : wom_f;
    const float* bo           = flow ? bo_g  : bo_f;
    float*       ldp          = flow ? ld_g  : ld_f;

    // ---- Xf[0] init: wave's 16 rows, coalesced float4 (wave-private) ----
    {
        const int row = ln >> 2;
        const int c0  = (ln & 3) * 16;
        const float* srcr = xin + (size_t)(r0 + row) * DIMS + c0;
        float* dstr = &Xf[0][wv][row][c0];
        #pragma unroll
        for (int i = 0; i < 4; ++i)
            *(float4*)(dstr + i * 4) = *(const float4*)(srcr + i * 4);
    }
    asm volatile("" ::: "memory");

    // ---- prologue: DMA-stage (layer 0, group 0) weights ----
    {
        const unsigned short* src = wom + ln * 8;
        #pragma unroll
        for (int i = 0; i < 6; ++i) {
            const int c = wv + 4 * i;
            if (c < 23) stage16(src + c * 512, Wl + c * 512);
        }
    }

    // ---- bias prefetch for (0,0) ----
    float bnx[6];
    #pragma unroll
    for (int nt = 0; nt < 6; ++nt)
        bnx[nt] = bo[nt * 16 + m] * LOG2E;     // g=0 cols 0..95 all in-bounds

    float ldsum = 0.0f;
    int cur = 0;
    unsigned short* sw = &S[wv][0];

    __syncthreads();                 // (0,0) weights resident for all waves

    #pragma unroll 1
    for (int l = 0; l < NLAYERS; ++l) {
        const unsigned short* w1m_l = w1m + (size_t)l * WID * DIMS;
        const float* b1_l           = b1 + (size_t)l * WID;
        const int nxt = cur ^ 1;

        // ---- GEMM1: A-frags from Xf[cur] (LDS, f32 -> bf16) ----
        s16x8 xa[2];
        #pragma unroll
        for (int ks = 0; ks < 2; ++ks) {
            float4 v0 = *(const float4*)&Xf[cur][wv][m][ks * 32 + q * 8];
            float4 v1 = *(const float4*)&Xf[cur][wv][m][ks * 32 + q * 8 + 4];
            s16x8 a;
            a[0] = (short)f2bf(v0.x); a[1] = (short)f2bf(v0.y);
            a[2] = (short)f2bf(v0.z); a[3] = (short)f2bf(v0.w);
            a[4] = (short)f2bf(v1.x); a[5] = (short)f2bf(v1.y);
            a[6] = (short)f2bf(v1.z); a[7] = (short)f2bf(v1.w);
            xa[ks] = a;
        }

        f32x4 hacc[8];
        #pragma unroll
        for (int nt = 0; nt < 8; ++nt) {
            float bv = b1_l[nt * 16 + m];
            hacc[nt] = (f32x4){bv, bv, bv, bv};
        }
        #pragma unroll
        for (int ks = 0; ks < 2; ++ks) {
            #pragma unroll
            for (int nt = 0; nt < 8; ++nt) {
                s16x8 bfr = *(const s16x8*)(w1m_l + (nt * 16 + m) * DIMS + ks * 32 + q * 8);
                hacc[nt] = __builtin_amdgcn_mfma_f32_16x16x32_bf16(xa[ks], bfr, hacc[nt], 0, 0, 0);
            }
        }
        // ReLU -> bf16 -> Hs view of S (lane: col h = nt*16+m, rows q*4+rr)
        #pragma unroll
        for (int nt = 0; nt < 8; ++nt) {
            #pragma unroll
            for (int rr = 0; rr < 4; ++rr) {
                sw[(q * 4 + rr) * 136 + nt * 16 + m] = f2bf(fmaxf(hacc[nt][rr], 0.0f));
            }
        }
        asm volatile("" ::: "memory");   // pin Hs stores before af loads

        // ---- A-frags for GEMM2 from Hs (b128, wave-private) ----
        s16x8 af[4];
        #pragma unroll
        for (int ks = 0; ks < 4; ++ks)
            af[ks] = *(const s16x8*)&sw[m * 136 + ks * 32 + q * 8];
        asm volatile("" ::: "memory");   // af read before Pc overwrites Hs

        #pragma unroll 1
        for (int g = 0; g < NGRP; ++g) {
            const int gi = l * NGRP + g;     // flat group 0..127

            // ---- GEMM2 group from Wl (swizzled): layer-local cols [92g,+96) ----
            f32x4 acc[6];
            #pragma unroll
            for (int nt = 0; nt < 6; ++nt)
                acc[nt] = (f32x4){bnx[nt], bnx[nt], bnx[nt], bnx[nt]};

            const int swz = ((g * 4 + m) & 7) << 4;  // (92g+16nt+m)&7 == (4g+m)&7
            #pragma unroll
            for (int ks = 0; ks < 4; ++ks) {
                #pragma unroll
                for (int nt = 0; nt < 6; ++nt) {
                    const s16x8 bfr = *(const s16x8*)&Wl[
                        (nt * 16 + m) * WID + ((ks * 32 + q * 8) ^ swz)];
                    acc[nt] = __builtin_amdgcn_mfma_f32_16x16x32_bf16(af[ks], bfr, acc[nt], 0, 0, 0);
                }
            }

            if (gi < NLAYERS * NGRP - 1) {
                __syncthreads();             // B1: all waves done reading Wl
                // DMA next flat group (crosses layer boundary) + bias prefetch.
                const int l2 = (gi + 1) >> 4;
                const int g2 = (gi + 1) & 15;
                const unsigned short* src = wom +
                    ((size_t)l2 * NCOL + (size_t)g2 * GRP) * WID + ln * 8;
                #pragma unroll
                for (int i = 0; i < 6; ++i) {
                    const int c = wv + 4 * i;
                    if (c < 23) stage16(src + c * 512, Wl + c * 512);
                }
                #pragma unroll
                for (int nt = 0; nt < 6; ++nt) {
                    int o = g2 * GRP + nt * 16 + m;
                    o = (o < NCOL) ? o : (NCOL - 1);
                    bnx[nt] = bo[(size_t)l2 * NCOL + o] * LOG2E;
                }
            }

            // P -> Pc view of S, col-major pitch 18 (RNE bf16 u16 stores).
            #pragma unroll
            for (int nt = 0; nt < 6; ++nt) {
                const int c18 = (nt * 16 + m) * 18 + q * 4;
                #pragma unroll
                for (int rr = 0; rr < 4; ++rr)
                    sw[c18 + rr] = f2bf(acc[nt][rr]);
            }

            // ---- spline: 4 dims x 16 rows, lane = (b=m, dim q). pp is
            //      pre-scaled by log2e: exp2f(pp) == e^{P_raw}. ----
            {
                const int d = g * 4 + q;

                float pp[NP];
                #pragma unroll
                for (int j = 0; j < NP; ++j)
                    pp[j] = bf2f(sw[(q * 23 + j) * 18 + m]);

                const float xraw = Xf[cur][wv][m][d];

                float ew[KN], eh[KN];
                #pragma unroll
                for (int j = 0; j < KN; ++j) {
                    ew[j] = exp2f(pp[j]);
                    eh[j] = exp2f(pp[8 + j]);
                }
                const float sw_ = ((ew[0] + ew[1]) + (ew[2] + ew[3]))
                                + ((ew[4] + ew[5]) + (ew[6] + ew[7]));
                const float sh_ = ((eh[0] + eh[1]) + (eh[2] + eh[3]))
                                + ((eh[4] + eh[5]) + (eh[6] + eh[7]));
                const float cmul = 8.0f / 1.01f;     // 2*Bi/(1+ADJ)
                const float cadd = 0.00125f * (8.0f / 1.01f);
                const float rw = cmul / sw_, rh = cmul / sh_;
                float width[KN], height[KN];
                #pragma unroll
                for (int j = 0; j < KN; ++j) {
                    width[j]  = fmaf(ew[j], rw, cadd);
                    height[j] = fmaf(eh[j], rh, cadd);
                }
                float dv[KN + 1];
                dv[0] = 1.0f; dv[KN] = 1.0f;
                #pragma unroll
                for (int i = 1; i < KN; ++i) {
                    const float tt = exp2f(pp[15 + i]);
                    dv[i] = fmaf(__log2f(1.0f + tt), 0.69314718f, 0.001f);
                }

                const bool inside = (xraw > -BI_F) && (xraw < BI_F);
                const float xcl = fminf(fmaxf(xraw, -BI_F), BI_F);

                float cx = -BI_F, cy = -BI_F;
                float xk = -BI_F, yk = -BI_F, xk1 = 0.f, yk1 = 0.f, dk = 1.f, dk1 = 1.f;
                #pragma unroll
                for (int i = 0; i < KN; ++i) {
                    const float nx = cx + width[i];
                    const float ny = cy + height[i];
                    const bool cc = (xcl >= cx);
                    xk  = cc ? cx : xk;    yk  = cc ? cy : yk;
                    xk1 = cc ? nx : xk1;   yk1 = cc ? ny : yk1;
                    dk  = cc ? dv[i] : dk; dk1 = cc ? dv[i + 1] : dk1;
                    cx = nx; cy = ny;
                }

                const float invw = 1.0f / (xk1 - xk);
                const float sk   = (yk1 - yk) * invw;
                const float xi   = (xcl - xk) * invw;
                const float omx  = 1.0f - xi;
                const float den  = sk + (dk1 + dk - 2.0f * sk) * xi * omx;
                const float rden = 1.0f / den;
                float outv = fmaf((yk1 - yk) * (sk * xi * xi + dk * xi * omx), rden, yk);
                const float numl = dk1 * xi * xi + 2.0f * sk * xi * omx + dk * omx * omx;
                float ldj = __logf(sk * sk * numl * rden * rden);
                outv = inside ? outv : xraw;
                ldj  = inside ? ldj : 0.0f;

                // flipped write into next x buffer (wave-private rows)
                Xf[nxt][wv][m][DIMS - 1 - d] = outv;
                ldsum += ldj;
            }

            if (gi < NLAYERS * NGRP - 1) {
                __syncthreads();             // B2: drains DMA for all waves
            }
        }

        cur ^= 1;
    }

    asm volatile("" ::: "memory");

    // ---- epilogue: coalesced xout write from final Xf buffer ----
    {
        const int row = ln >> 2;
        const int c0  = (ln & 3) * 16;
        const float* srcr = &Xf[cur][wv][row][c0];
        float* dstr = xout + (size_t)(r0 + row) * DIMS + c0;
        #pragma unroll
        for (int i = 0; i < 4; ++i)
            *(float4*)(dstr + i * 4) = *(const float4*)(srcr + i * 4);
    }

    // ---- ld: reduce q-quarters, ONE plain store per row (exclusive owner,
    //      overwrites harness poison) ----
    float v = ldsum + __shfl_xor(ldsum, 16, 64);
    v = v + __shfl_xor(v, 32, 64);
    if (ln < 16) {
        ldp[r0 + ln] = v;
    }
}

// ---------------------------------------------------------------------------
extern "C" void kernel_launch(void* const* d_in, const int* in_sizes, int n_in,
                              void* d_out, int out_size, void* d_ws, size_t ws_size,
                              hipStream_t stream)
{
    const float* x      = (const float*)d_in[0];
    const float* y      = (const float*)d_in[1];
    const float* f_W1   = (const float*)d_in[2];
    const float* f_b1   = (const float*)d_in[3];
    const float* f_Wout = (const float*)d_in[4];
    const float* f_bout = (const float*)d_in[5];
    const float* g_W1   = (const float*)d_in[6];
    const float* g_b1   = (const float*)d_in[7];
    const float* g_Wout = (const float*)d_in[8];
    const float* g_bout = (const float*)d_in[9];

    float* out = (float*)d_out;
    float* xo  = out;                               // [B, D]
    float* ldf = out + (size_t)BATCH * DIMS;        // [B]
    float* yo  = ldf + BATCH;                       // [B, D]
    float* ldg = yo + (size_t)BATCH * DIMS;         // [B]

    // Workspace: womask + w1mask only (x ping buffers no longer needed).
    unsigned short* womask = (unsigned short*)d_ws;           // 2*PF_WOUT bf16
    unsigned short* w1mask = womask + 2 * (size_t)PF_WOUT;    // 2*PF_W1 bf16

    premask_kernel<<<dim3(2048), dim3(256), 0, stream>>>(
        f_Wout, g_Wout, f_W1, g_W1, womask, w1mask);

    flow8_kernel<<<dim3(BATCH / 64, 2), dim3(256), 0, stream>>>(
        x, y, xo, yo,
        w1mask, w1mask + (size_t)PF_W1,
        f_b1, g_b1,
        womask, womask + (size_t)PF_WOUT,
        f_bout, g_bout,
        ldf, ldg);
}

// Round 10
// 438.283 us; speedup vs baseline: 2.0618x; 1.0356x over previous
//
#include <hip/hip_runtime.h>
#include <math.h>

#define BATCH   16384
#define DIMS    64
#define WID     128
#define KN      8
#define NP      23        // 3*KN - 1
#define NCOL    (DIMS * NP)   // 1472 param columns
#define NLAYERS 8
#define BI_F    4.0f
#define GRP     92        // param cols per 4-dim group
#define NGRP    16        // groups per layer (full 64 dims per block)
#define XPITCH  68        // Xf row pitch in floats (68%32=4 -> 2-way free)
#define LOG2E   1.44269504f

#define PF_WOUT (NLAYERS * NCOL * WID)        // per-flow Wout elems: 1,507,328
#define PF_W1   (NLAYERS * WID * DIMS)        // per-flow W1 elems:   65,536

typedef short s16x8 __attribute__((ext_vector_type(8)));
typedef float f32x4 __attribute__((ext_vector_type(4)));

__device__ __forceinline__ unsigned short f2bf(float f) {
    unsigned int u = __builtin_bit_cast(unsigned int, f);
    unsigned int r = (u + 0x7FFFu + ((u >> 16) & 1u)) >> 16;
    return (unsigned short)r;
}
__device__ __forceinline__ float bf2f(unsigned short u) {
    return __builtin_bit_cast(float, (unsigned int)u << 16);
}
// HW packed f32->bf16 RNE: dst = {bf16(a) in lo16, bf16(b) in hi16}.
// 1 instruction per pair vs 4-op software RNE per value (bit-identical
// rounding; no builtin on gfx950 -> inline asm, pure VALU, reg constraints
// only so the scheduler tracks deps normally).
__device__ __forceinline__ unsigned int cvtpk_bf16(float a, float b) {
    unsigned int r;
    asm("v_cvt_pk_bf16_f32 %0, %1, %2" : "=v"(r) : "v"(a), "v"(b));
    return r;
}

// global -> LDS direct DMA, 16B per lane. LDS dest is wave-uniform base +
// lane*16 (HW rule); global src is per-lane.
__device__ __forceinline__ void stage16(const unsigned short* g, unsigned short* l) {
    __builtin_amdgcn_global_load_lds(
        (__attribute__((address_space(1))) void*)g,
        (__attribute__((address_space(3))) void*)l,
        16, 0, 0);
}

// ---------------------------------------------------------------------------
// Pre-mask MADE weights -> bf16 workspace. womask is stored K-SWIZZLED within
// each 128-short column: k -> k ^ ((col&7)<<4); the linear global_load_lds
// lands the swizzled layout in LDS and the ds_read_b128 B-fragment reads XOR
// the same key (conflict-light, 8-short runs intact). womask PRE-SCALED by
// log2e (all P param cols are consumed through exp/softplus-exp only), so
// the spline uses exp2f with no multiply. W1 NOT scaled (feeds H).
// ---------------------------------------------------------------------------
__global__ __launch_bounds__(256) void premask_kernel(
    const float* __restrict__ f_wout, const float* __restrict__ g_wout,
    const float* __restrict__ f_w1,   const float* __restrict__ g_w1,
    unsigned short* __restrict__ womask, unsigned short* __restrict__ w1mask)
{
    const int idx    = blockIdx.x * 256 + threadIdx.x;
    const int stride = gridDim.x * 256;

    const int totw = 2 * PF_WOUT;
    for (int i = idx; i < totw; i += stride) {
        int fl = i / PF_WOUT;
        int r  = i % PF_WOUT;
        int h  = r % WID;
        int o  = (r / WID) % NCOL;              // layer-local param col
        int d  = o / NP;
        int hd = h % (DIMS - 1) + 1;            // hid_deg
        const float* src = fl ? g_wout : f_wout;
        unsigned short v = (hd <= d) ? f2bf(src[r] * LOG2E) : (unsigned short)0;
        const int dst = i - h + (h ^ ((o & 7) << 4));   // swizzled k position
        womask[dst] = v;
    }

    const int tot1 = 2 * PF_W1;
    for (int i = idx; i < tot1; i += stride) {
        int fl = i / PF_W1;
        int r  = i % PF_W1;
        int c  = r % DIMS;
        int w  = (r / DIMS) % WID;
        int deg = w % (DIMS - 1) + 1;           // hid_deg
        const float* src = fl ? g_w1 : f_w1;
        w1mask[i] = (c < deg) ? f2bf(src[r]) : (unsigned short)0;
    }
}

// ---------------------------------------------------------------------------
// FUSED 8-layer MAF kernel. Grid (BATCH/64, 2): blockIdx.y = flow. Block =
// 4 waves, 64 batch rows, ALL 64 dims, loops all 8 layers in-block.
//   - x in double-buffered LDS ping-pong Xf[2] (f32, wave-private rows).
//   - flat 128-group schedule; single-buffer Wl pipeline
//     {MFMA -> B1 -> DMA(next)+bias prefetch -> Pc+spline -> B2} crossing
//     layer boundaries; GEMM1 of l+1 slots between B2(l,15) and MFMA(l+1,0).
//   - ld accumulates in-register across layers; one plain store at the end.
// ROUND 10 (VALU diet, counters: VALUBusy 65% dominant): all f32->bf16
// conversions via HW v_cvt_pk_bf16_f32 (1 inst/pair vs 4 ops/value software
// RNE; bit-identical rounding -> absmax unchanged; u16 stores kept -> no
// memory-model change). Knot-scan i=0 peeled (cc always true after clamp).
// LDS: Wl 23,552 + S 17,408 + Xf 34,816 = 75,776 B -> 2 blocks/CU.
// ---------------------------------------------------------------------------
__global__ __launch_bounds__(256)
__attribute__((amdgpu_waves_per_eu(2, 2)))
void flow8_kernel(
    const float* __restrict__ xin_f, const float* __restrict__ xin_g,
    float* __restrict__ xout_f,      float* __restrict__ xout_g,
    const unsigned short* __restrict__ w1m_f, const unsigned short* __restrict__ w1m_g,
    const float* __restrict__ b1_f,  const float* __restrict__ b1_g,
    const unsigned short* __restrict__ wom_f, const unsigned short* __restrict__ wom_g,
    const float* __restrict__ bo_f,  const float* __restrict__ bo_g,
    float* __restrict__ ld_f,        float* __restrict__ ld_g)
{
    // Wl: staged weight tile, linear [92 cols][128 k] (k pre-swizzled).
    __shared__ __align__(16) unsigned short Wl[GRP * WID];        // 23,552 B
    // S: per-wave overlay. Hs view [16][136] u16; Pc view col-major [96][18].
    __shared__ __align__(16) unsigned short S[4][2176];           // 17,408 B
    // Xf: x ping-pong, per-wave 16 rows x 64 dims f32 (pitch 68: 2-way free).
    __shared__ __align__(16) float Xf[2][4][16][XPITCH];          // 34,816 B

    const int t    = threadIdx.x;
    const int wv   = t >> 6;          // wave 0..3
    const int ln   = t & 63;
    const int m    = ln & 15;         // row-in-tile / col-in-tile index
    const int q    = ln >> 4;         // quad
    const int flow = blockIdx.y;
    const int r0   = blockIdx.x * 64 + wv * 16;   // this wave's first batch row

    const float* xin          = flow ? xin_g : xin_f;
    float*       xout         = flow ? xout_g : xout_f;
    const unsigned short* w1m = flow ? w1m_g : w1m_f;
    const float* b1           = flow ? b1_g  : b1_f;
    const unsigned short* wom = flow ? wom_g : wom_f;
    const float* bo           = flow ? bo_g  : bo_f;
    float*       ldp          = flow ? ld_g  : ld_f;

    // ---- Xf[0] init: wave's 16 rows, coalesced float4 (wave-private) ----
    {
        const int row = ln >> 2;
        const int c0  = (ln & 3) * 16;
        const float* srcr = xin + (size_t)(r0 + row) * DIMS + c0;
        float* dstr = &Xf[0][wv][row][c0];
        #pragma unroll
        for (int i = 0; i < 4; ++i)
            *(float4*)(dstr + i * 4) = *(const float4*)(srcr + i * 4);
    }
    asm volatile("" ::: "memory");

    // ---- prologue: DMA-stage (layer 0, group 0) weights ----
    {
        const unsigned short* src = wom + ln * 8;
        #pragma unroll
        for (int i = 0; i < 6; ++i) {
            const int c = wv + 4 * i;
            if (c < 23) stage16(src + c * 512, Wl + c * 512);
        }
    }

    // ---- bias prefetch for (0,0) ----
    float bnx[6];
    #pragma unroll
    for (int nt = 0; nt < 6; ++nt)
        bnx[nt] = bo[nt * 16 + m] * LOG2E;     // g=0 cols 0..95 all in-bounds

    float ldsum = 0.0f;
    int cur = 0;
    unsigned short* sw = &S[wv][0];

    __syncthreads();                 // (0,0) weights resident for all waves

    #pragma unroll 1
    for (int l = 0; l < NLAYERS; ++l) {
        const unsigned short* w1m_l = w1m + (size_t)l * WID * DIMS;
        const float* b1_l           = b1 + (size_t)l * WID;
        const int nxt = cur ^ 1;

        // ---- GEMM1: A-frags from Xf[cur] (LDS, f32 -> bf16 via cvt_pk) ----
        s16x8 xa[2];
        #pragma unroll
        for (int ks = 0; ks < 2; ++ks) {
            float4 v0 = *(const float4*)&Xf[cur][wv][m][ks * 32 + q * 8];
            float4 v1 = *(const float4*)&Xf[cur][wv][m][ks * 32 + q * 8 + 4];
            uint4 uu;
            uu.x = cvtpk_bf16(v0.x, v0.y);
            uu.y = cvtpk_bf16(v0.z, v0.w);
            uu.z = cvtpk_bf16(v1.x, v1.y);
            uu.w = cvtpk_bf16(v1.z, v1.w);
            xa[ks] = __builtin_bit_cast(s16x8, uu);
        }

        f32x4 hacc[8];
        #pragma unroll
        for (int nt = 0; nt < 8; ++nt) {
            float bv = b1_l[nt * 16 + m];
            hacc[nt] = (f32x4){bv, bv, bv, bv};
        }
        #pragma unroll
        for (int ks = 0; ks < 2; ++ks) {
            #pragma unroll
            for (int nt = 0; nt < 8; ++nt) {
                s16x8 bfr = *(const s16x8*)(w1m_l + (nt * 16 + m) * DIMS + ks * 32 + q * 8);
                hacc[nt] = __builtin_amdgcn_mfma_f32_16x16x32_bf16(xa[ks], bfr, hacc[nt], 0, 0, 0);
            }
        }
        // ReLU -> bf16 (cvt_pk pairs) -> Hs view of S (u16 stores, rows are
        // strided so pairs split into two u16 each).
        #pragma unroll
        for (int nt = 0; nt < 8; ++nt) {
            const int c = nt * 16 + m;
            unsigned int p0 = cvtpk_bf16(fmaxf(hacc[nt][0], 0.0f),
                                         fmaxf(hacc[nt][1], 0.0f));
            unsigned int p1 = cvtpk_bf16(fmaxf(hacc[nt][2], 0.0f),
                                         fmaxf(hacc[nt][3], 0.0f));
            sw[(q * 4 + 0) * 136 + c] = (unsigned short)p0;
            sw[(q * 4 + 1) * 136 + c] = (unsigned short)(p0 >> 16);
            sw[(q * 4 + 2) * 136 + c] = (unsigned short)p1;
            sw[(q * 4 + 3) * 136 + c] = (unsigned short)(p1 >> 16);
        }
        asm volatile("" ::: "memory");   // pin Hs stores before af loads

        // ---- A-frags for GEMM2 from Hs (b128, wave-private) ----
        s16x8 af[4];
        #pragma unroll
        for (int ks = 0; ks < 4; ++ks)
            af[ks] = *(const s16x8*)&sw[m * 136 + ks * 32 + q * 8];
        asm volatile("" ::: "memory");   // af read before Pc overwrites Hs

        #pragma unroll 1
        for (int g = 0; g < NGRP; ++g) {
            const int gi = l * NGRP + g;     // flat group 0..127

            // ---- GEMM2 group from Wl (swizzled): layer-local cols [92g,+96) ----
            f32x4 acc[6];
            #pragma unroll
            for (int nt = 0; nt < 6; ++nt)
                acc[nt] = (f32x4){bnx[nt], bnx[nt], bnx[nt], bnx[nt]};

            const int swz = ((g * 4 + m) & 7) << 4;  // (92g+16nt+m)&7 == (4g+m)&7
            #pragma unroll
            for (int ks = 0; ks < 4; ++ks) {
                #pragma unroll
                for (int nt = 0; nt < 6; ++nt) {
                    const s16x8 bfr = *(const s16x8*)&Wl[
                        (nt * 16 + m) * WID + ((ks * 32 + q * 8) ^ swz)];
                    acc[nt] = __builtin_amdgcn_mfma_f32_16x16x32_bf16(af[ks], bfr, acc[nt], 0, 0, 0);
                }
            }

            if (gi < NLAYERS * NGRP - 1) {
                __syncthreads();             // B1: all waves done reading Wl
                // DMA next flat group (crosses layer boundary) + bias prefetch.
                const int l2 = (gi + 1) >> 4;
                const int g2 = (gi + 1) & 15;
                const unsigned short* src = wom +
                    ((size_t)l2 * NCOL + (size_t)g2 * GRP) * WID + ln * 8;
                #pragma unroll
                for (int i = 0; i < 6; ++i) {
                    const int c = wv + 4 * i;
                    if (c < 23) stage16(src + c * 512, Wl + c * 512);
                }
                #pragma unroll
                for (int nt = 0; nt < 6; ++nt) {
                    int o = g2 * GRP + nt * 16 + m;
                    o = (o < NCOL) ? o : (NCOL - 1);
                    bnx[nt] = bo[(size_t)l2 * NCOL + o] * LOG2E;
                }
            }

            // P -> Pc view of S, col-major pitch 18. cvt_pk pairs (RNE),
            // split to u16 stores (rows contiguous -> compiler re-merges).
            #pragma unroll
            for (int nt = 0; nt < 6; ++nt) {
                const int c18 = (nt * 16 + m) * 18 + q * 4;
                unsigned int p0 = cvtpk_bf16(acc[nt][0], acc[nt][1]);
                unsigned int p1 = cvtpk_bf16(acc[nt][2], acc[nt][3]);
                sw[c18 + 0] = (unsigned short)p0;
                sw[c18 + 1] = (unsigned short)(p0 >> 16);
                sw[c18 + 2] = (unsigned short)p1;
                sw[c18 + 3] = (unsigned short)(p1 >> 16);
            }

            // ---- spline: 4 dims x 16 rows, lane = (b=m, dim q). pp is
            //      pre-scaled by log2e: exp2f(pp) == e^{P_raw}. ----
            {
                const int d = g * 4 + q;

                float pp[NP];
                #pragma unroll
                for (int j = 0; j < NP; ++j)
                    pp[j] = bf2f(sw[(q * 23 + j) * 18 + m]);

                const float xraw = Xf[cur][wv][m][d];

                float ew[KN], eh[KN];
                #pragma unroll
                for (int j = 0; j < KN; ++j) {
                    ew[j] = exp2f(pp[j]);
                    eh[j] = exp2f(pp[8 + j]);
                }
                const float sw_ = ((ew[0] + ew[1]) + (ew[2] + ew[3]))
                                + ((ew[4] + ew[5]) + (ew[6] + ew[7]));
                const float sh_ = ((eh[0] + eh[1]) + (eh[2] + eh[3]))
                                + ((eh[4] + eh[5]) + (eh[6] + eh[7]));
                const float cmul = 8.0f / 1.01f;     // 2*Bi/(1+ADJ)
                const float cadd = 0.00125f * (8.0f / 1.01f);
                const float rw = cmul / sw_, rh = cmul / sh_;
                float width[KN], height[KN];
                #pragma unroll
                for (int j = 0; j < KN; ++j) {
                    width[j]  = fmaf(ew[j], rw, cadd);
                    height[j] = fmaf(eh[j], rh, cadd);
                }
                float dv[KN + 1];
                dv[0] = 1.0f; dv[KN] = 1.0f;
                #pragma unroll
                for (int i = 1; i < KN; ++i) {
                    const float tt = exp2f(pp[15 + i]);
                    dv[i] = fmaf(__log2f(1.0f + tt), 0.69314718f, 0.001f);
                }

                const bool inside = (xraw > -BI_F) && (xraw < BI_F);
                const float xcl = fminf(fmaxf(xraw, -BI_F), BI_F);

                // i=0 peeled: xcl >= -Bi always after clamp -> direct init.
                float cx = -BI_F + width[0], cy = -BI_F + height[0];
                float xk = -BI_F, yk = -BI_F, xk1 = cx, yk1 = cy;
                float dk = 1.0f, dk1 = dv[1];
                #pragma unroll
                for (int i = 1; i < KN; ++i) {
                    const float nx = cx + width[i];
                    const float ny = cy + height[i];
                    const bool cc = (xcl >= cx);
                    xk  = cc ? cx : xk;    yk  = cc ? cy : yk;
                    xk1 = cc ? nx : xk1;   yk1 = cc ? ny : yk1;
                    dk  = cc ? dv[i] : dk; dk1 = cc ? dv[i + 1] : dk1;
                    cx = nx; cy = ny;
                }

                const float invw = 1.0f / (xk1 - xk);
                const float sk   = (yk1 - yk) * invw;
                const float xi   = (xcl - xk) * invw;
                const float omx  = 1.0f - xi;
                const float den  = sk + (dk1 + dk - 2.0f * sk) * xi * omx;
                const float rden = 1.0f / den;
                float outv = fmaf((yk1 - yk) * (sk * xi * xi + dk * xi * omx), rden, yk);
                const float numl = dk1 * xi * xi + 2.0f * sk * xi * omx + dk * omx * omx;
                float ldj = __logf(sk * sk * numl * rden * rden);
                outv = inside ? outv : xraw;
                ldj  = inside ? ldj : 0.0f;

                // flipped write into next x buffer (wave-private rows)
                Xf[nxt][wv][m][DIMS - 1 - d] = outv;
                ldsum += ldj;
            }

            if (gi < NLAYERS * NGRP - 1) {
                __syncthreads();             // B2: drains DMA for all waves
            }
        }

        cur ^= 1;
    }

    asm volatile("" ::: "memory");

    // ---- epilogue: coalesced xout write from final Xf buffer ----
    {
        const int row = ln >> 2;
        const int c0  = (ln & 3) * 16;
        const float* srcr = &Xf[cur][wv][row][c0];
        float* dstr = xout + (size_t)(r0 + row) * DIMS + c0;
        #pragma unroll
        for (int i = 0; i < 4; ++i)
            *(float4*)(dstr + i * 4) = *(const float4*)(srcr + i * 4);
    }

    // ---- ld: reduce q-quarters, ONE plain store per row (exclusive owner,
    //      overwrites harness poison) ----
    float v = ldsum + __shfl_xor(ldsum, 16, 64);
    v = v + __shfl_xor(v, 32, 64);
    if (ln < 16) {
        ldp[r0 + ln] = v;
    }
}

// ---------------------------------------------------------------------------
extern "C" void kernel_launch(void* const* d_in, const int* in_sizes, int n_in,
                              void* d_out, int out_size, void* d_ws, size_t ws_size,
                              hipStream_t stream)
{
    const float* x      = (const float*)d_in[0];
    const float* y      = (const float*)d_in[1];
    const float* f_W1   = (const float*)d_in[2];
    const float* f_b1   = (const float*)d_in[3];
    const float* f_Wout = (const float*)d_in[4];
    const float* f_bout = (const float*)d_in[5];
    const float* g_W1   = (const float*)d_in[6];
    const float* g_b1   = (const float*)d_in[7];
    const float* g_Wout = (const float*)d_in[8];
    const float* g_bout = (const float*)d_in[9];

    float* out = (float*)d_out;
    float* xo  = out;                               // [B, D]
    float* ldf = out + (size_t)BATCH * DIMS;        // [B]
    float* yo  = ldf + BATCH;                       // [B, D]
    float* ldg = yo + (size_t)BATCH * DIMS;         // [B]

    // Workspace: womask + w1mask only.
    unsigned short* womask = (unsigned short*)d_ws;           // 2*PF_WOUT bf16
    unsigned short* w1mask = womask + 2 * (size_t)PF_WOUT;    // 2*PF_W1 bf16

    premask_kernel<<<dim3(2048), dim3(256), 0, stream>>>(
        f_Wout, g_Wout, f_W1, g_W1, womask, w1mask);

    flow8_kernel<<<dim3(BATCH / 64, 2), dim3(256), 0, stream>>>(
        x, y, xo, yo,
        w1mask, w1mask + (size_t)PF_W1,
        f_b1, g_b1,
        womask, womask + (size_t)PF_WOUT,
        f_bout, g_bout,
        ldf, ldg);
}

// Round 11
// 427.204 us; speedup vs baseline: 2.1153x; 1.0259x over previous
//
#include <hip/hip_runtime.h>
#include <math.h>

#define BATCH   16384
#define DIMS    64
#define WID     128
#define KN      8
#define NP      23        // 3*KN - 1
#define NCOL    (DIMS * NP)   // 1472 param columns
#define NLAYERS 8
#define BI_F    4.0f
#define GRP     92        // param cols per 4-dim group
#define NGRP    16        // groups per layer (full 64 dims per block)
#define XPITCH  68        // Xf row pitch in floats (68%32=4 -> 2-way free)
#define PCP     104       // Pc row pitch in shorts (208 B, 16B-aligned rows)
#define LOG2E   1.44269504f

#define PF_WOUT (NLAYERS * NCOL * WID)        // per-flow Wout elems: 1,507,328
#define PF_W1   (NLAYERS * WID * DIMS)        // per-flow W1 elems:   65,536

typedef short s16x8 __attribute__((ext_vector_type(8)));
typedef unsigned short u16x8 __attribute__((ext_vector_type(8)));
typedef float f32x4 __attribute__((ext_vector_type(4)));

__device__ __forceinline__ unsigned short f2bf(float f) {
    unsigned int u = __builtin_bit_cast(unsigned int, f);
    unsigned int r = (u + 0x7FFFu + ((u >> 16) & 1u)) >> 16;
    return (unsigned short)r;
}
// bf16-pair dword -> two f32 (lo half: shift up; hi half: mask in place).
__device__ __forceinline__ float bfLO(unsigned int u) {
    return __builtin_bit_cast(float, u << 16);
}
__device__ __forceinline__ float bfHI(unsigned int u) {
    return __builtin_bit_cast(float, u & 0xffff0000u);
}
// HW packed f32->bf16 RNE: dst = {bf16(a) lo16, bf16(b) hi16}. 1 inst/pair.
__device__ __forceinline__ unsigned int cvtpk_bf16(float a, float b) {
    unsigned int r;
    asm("v_cvt_pk_bf16_f32 %0, %1, %2" : "=v"(r) : "v"(a), "v"(b));
    return r;
}

// global -> LDS direct DMA, 16B per lane. LDS dest is wave-uniform base +
// lane*16 (HW rule); global src is per-lane.
__device__ __forceinline__ void stage16(const unsigned short* g, unsigned short* l) {
    __builtin_amdgcn_global_load_lds(
        (__attribute__((address_space(1))) void*)g,
        (__attribute__((address_space(3))) void*)l,
        16, 0, 0);
}

// ---------------------------------------------------------------------------
// Pre-mask MADE weights -> bf16 workspace. womask is stored K-SWIZZLED within
// each 128-short column: k -> k ^ ((col&7)<<4); the linear global_load_lds
// lands the swizzled layout in LDS and the ds_read_b128 B-fragment reads XOR
// the same key (conflict-light, 8-short runs intact). womask PRE-SCALED by
// log2e (all P param cols are consumed through exp/softplus-exp only), so
// the spline uses exp2f with no multiply. W1 NOT scaled (feeds H).
// ---------------------------------------------------------------------------
__global__ __launch_bounds__(256) void premask_kernel(
    const float* __restrict__ f_wout, const float* __restrict__ g_wout,
    const float* __restrict__ f_w1,   const float* __restrict__ g_w1,
    unsigned short* __restrict__ womask, unsigned short* __restrict__ w1mask)
{
    const int idx    = blockIdx.x * 256 + threadIdx.x;
    const int stride = gridDim.x * 256;

    const int totw = 2 * PF_WOUT;
    for (int i = idx; i < totw; i += stride) {
        int fl = i / PF_WOUT;
        int r  = i % PF_WOUT;
        int h  = r % WID;
        int o  = (r / WID) % NCOL;              // layer-local param col
        int d  = o / NP;
        int hd = h % (DIMS - 1) + 1;            // hid_deg
        const float* src = fl ? g_wout : f_wout;
        unsigned short v = (hd <= d) ? f2bf(src[r] * LOG2E) : (unsigned short)0;
        const int dst = i - h + (h ^ ((o & 7) << 4));   // swizzled k position
        womask[dst] = v;
    }

    const int tot1 = 2 * PF_W1;
    for (int i = idx; i < tot1; i += stride) {
        int fl = i / PF_W1;
        int r  = i % PF_W1;
        int c  = r % DIMS;
        int w  = (r / DIMS) % WID;
        int deg = w % (DIMS - 1) + 1;           // hid_deg
        const float* src = fl ? g_w1 : f_w1;
        w1mask[i] = (c < deg) ? f2bf(src[r]) : (unsigned short)0;
    }
}

// ---------------------------------------------------------------------------
// FUSED 8-layer MAF kernel. Grid (BATCH/64, 2): blockIdx.y = flow. Block =
// 4 waves, 64 batch rows, ALL 64 dims, loops all 8 layers in-block.
//   - x in double-buffered LDS ping-pong Xf[2] (f32, wave-private rows).
//   - flat 128-group schedule; single-buffer Wl pipeline
//     {MFMA -> B1 -> DMA(next)+bias prefetch -> Pc+spline -> B2} crossing
//     layer boundaries.
//   - ld accumulates in-register across layers; one plain store at the end.
// ROUND 11 (VALU/issue diet; counters: VALUBusy 60% dominant, MFMA 11%):
//   (a) P staged ROW-major per (batch row, dim): dim q's 23 params sit at
//       cols q*24+j (write col off = o + dim(o), loop-invariant per nt; pad
//       cols never read; pitch 104 shorts = 208 B keeps rows 16B-aligned).
//       Spline reads 3x ds_read_b128 instead of 23x ds_read_u16.
//   (b) DEFERRED softplus: knot scan tracks the two SELECTED raw derivative
//       params (same cndmask count), softplus runs on exactly 2 values;
//       boundaries via cc1/cc7 (cc monotone in i). 7->2 exp2+log2.
// LDS: Wl 23,552 + S 17,408 + Xf 34,816 = 75,776 B -> 2 blocks/CU.
// ---------------------------------------------------------------------------
__global__ __launch_bounds__(256)
__attribute__((amdgpu_waves_per_eu(2, 2)))
void flow8_kernel(
    const float* __restrict__ xin_f, const float* __restrict__ xin_g,
    float* __restrict__ xout_f,      float* __restrict__ xout_g,
    const unsigned short* __restrict__ w1m_f, const unsigned short* __restrict__ w1m_g,
    const float* __restrict__ b1_f,  const float* __restrict__ b1_g,
    const unsigned short* __restrict__ wom_f, const unsigned short* __restrict__ wom_g,
    const float* __restrict__ bo_f,  const float* __restrict__ bo_g,
    float* __restrict__ ld_f,        float* __restrict__ ld_g)
{
    // Wl: staged weight tile, linear [92 cols][128 k] (k pre-swizzled).
    __shared__ __align__(16) unsigned short Wl[GRP * WID];        // 23,552 B
    // S: per-wave overlay. Hs view [16][136] u16 (2176); Pc view row-major
    //    [16 rows][104] u16 (1664). Hs dead before first Pc write.
    __shared__ __align__(16) unsigned short S[4][2176];           // 17,408 B
    // Xf: x ping-pong, per-wave 16 rows x 64 dims f32 (pitch 68: 2-way free).
    __shared__ __align__(16) float Xf[2][4][16][XPITCH];          // 34,816 B

    const int t    = threadIdx.x;
    const int wv   = t >> 6;          // wave 0..3
    const int ln   = t & 63;
    const int m    = ln & 15;         // row-in-tile / col-in-tile index
    const int q    = ln >> 4;         // quad
    const int flow = blockIdx.y;
    const int r0   = blockIdx.x * 64 + wv * 16;   // this wave's first batch row

    const float* xin          = flow ? xin_g : xin_f;
    float*       xout         = flow ? xout_g : xout_f;
    const unsigned short* w1m = flow ? w1m_g : w1m_f;
    const float* b1           = flow ? b1_g  : b1_f;
    const unsigned short* wom = flow ? wom_g : wom_f;
    const float* bo           = flow ? bo_g  : bo_f;
    float*       ldp          = flow ? ld_g  : ld_f;

    // ---- Xf[0] init: wave's 16 rows, coalesced float4 (wave-private) ----
    {
        const int row = ln >> 2;
        const int c0  = (ln & 3) * 16;
        const float* srcr = xin + (size_t)(r0 + row) * DIMS + c0;
        float* dstr = &Xf[0][wv][row][c0];
        #pragma unroll
        for (int i = 0; i < 4; ++i)
            *(float4*)(dstr + i * 4) = *(const float4*)(srcr + i * 4);
    }
    asm volatile("" ::: "memory");

    // ---- prologue: DMA-stage (layer 0, group 0) weights ----
    {
        const unsigned short* src = wom + ln * 8;
        #pragma unroll
        for (int i = 0; i < 6; ++i) {
            const int c = wv + 4 * i;
            if (c < 23) stage16(src + c * 512, Wl + c * 512);
        }
    }

    // ---- bias prefetch for (0,0) ----
    float bnx[6];
    #pragma unroll
    for (int nt = 0; nt < 6; ++nt)
        bnx[nt] = bo[nt * 16 + m] * LOG2E;     // g=0 cols 0..95 all in-bounds

    // ---- P-store column mapping, loop-invariant: col o = nt*16+m maps to
    //      (dim = o/23, j = o%23) -> row-major col off = dim*24+j = o+dim.
    //      Overlap cols o>=92 -> off 96..99 (pad, never read).
    int offn[6];
    #pragma unroll
    for (int nt = 0; nt < 6; ++nt) {
        const int o = nt * 16 + m;
        offn[nt] = o + (o >= 23) + (o >= 46) + (o >= 69) + (o >= 92);
    }

    float ldsum = 0.0f;
    int cur = 0;
    unsigned short* sw = &S[wv][0];

    __syncthreads();                 // (0,0) weights resident for all waves

    #pragma unroll 1
    for (int l = 0; l < NLAYERS; ++l) {
        const unsigned short* w1m_l = w1m + (size_t)l * WID * DIMS;
        const float* b1_l           = b1 + (size_t)l * WID;
        const int nxt = cur ^ 1;

        // ---- GEMM1: A-frags from Xf[cur] (LDS, f32 -> bf16 via cvt_pk) ----
        s16x8 xa[2];
        #pragma unroll
        for (int ks = 0; ks < 2; ++ks) {
            float4 v0 = *(const float4*)&Xf[cur][wv][m][ks * 32 + q * 8];
            float4 v1 = *(const float4*)&Xf[cur][wv][m][ks * 32 + q * 8 + 4];
            uint4 uu;
            uu.x = cvtpk_bf16(v0.x, v0.y);
            uu.y = cvtpk_bf16(v0.z, v0.w);
            uu.z = cvtpk_bf16(v1.x, v1.y);
            uu.w = cvtpk_bf16(v1.z, v1.w);
            xa[ks] = __builtin_bit_cast(s16x8, uu);
        }

        f32x4 hacc[8];
        #pragma unroll
        for (int nt = 0; nt < 8; ++nt) {
            float bv = b1_l[nt * 16 + m];
            hacc[nt] = (f32x4){bv, bv, bv, bv};
        }
        #pragma unroll
        for (int ks = 0; ks < 2; ++ks) {
            #pragma unroll
            for (int nt = 0; nt < 8; ++nt) {
                s16x8 bfr = *(const s16x8*)(w1m_l + (nt * 16 + m) * DIMS + ks * 32 + q * 8);
                hacc[nt] = __builtin_amdgcn_mfma_f32_16x16x32_bf16(xa[ks], bfr, hacc[nt], 0, 0, 0);
            }
        }
        // ReLU -> bf16 (cvt_pk pairs) -> Hs view of S (pitch 136).
        #pragma unroll
        for (int nt = 0; nt < 8; ++nt) {
            const int c = nt * 16 + m;
            unsigned int p0 = cvtpk_bf16(fmaxf(hacc[nt][0], 0.0f),
                                         fmaxf(hacc[nt][1], 0.0f));
            unsigned int p1 = cvtpk_bf16(fmaxf(hacc[nt][2], 0.0f),
                                         fmaxf(hacc[nt][3], 0.0f));
            sw[(q * 4 + 0) * 136 + c] = (unsigned short)p0;
            sw[(q * 4 + 1) * 136 + c] = (unsigned short)(p0 >> 16);
            sw[(q * 4 + 2) * 136 + c] = (unsigned short)p1;
            sw[(q * 4 + 3) * 136 + c] = (unsigned short)(p1 >> 16);
        }
        asm volatile("" ::: "memory");   // pin Hs stores before af loads

        // ---- A-frags for GEMM2 from Hs (b128, wave-private) ----
        s16x8 af[4];
        #pragma unroll
        for (int ks = 0; ks < 4; ++ks)
            af[ks] = *(const s16x8*)&sw[m * 136 + ks * 32 + q * 8];
        asm volatile("" ::: "memory");   // af read before Pc overwrites Hs

        #pragma unroll 1
        for (int g = 0; g < NGRP; ++g) {
            const int gi = l * NGRP + g;     // flat group 0..127

            // ---- GEMM2 group from Wl (swizzled): layer-local cols [92g,+96) ----
            f32x4 acc[6];
            #pragma unroll
            for (int nt = 0; nt < 6; ++nt)
                acc[nt] = (f32x4){bnx[nt], bnx[nt], bnx[nt], bnx[nt]};

            const int swz = ((g * 4 + m) & 7) << 4;  // (92g+16nt+m)&7 == (4g+m)&7
            #pragma unroll
            for (int ks = 0; ks < 4; ++ks) {
                #pragma unroll
                for (int nt = 0; nt < 6; ++nt) {
                    const s16x8 bfr = *(const s16x8*)&Wl[
                        (nt * 16 + m) * WID + ((ks * 32 + q * 8) ^ swz)];
                    acc[nt] = __builtin_amdgcn_mfma_f32_16x16x32_bf16(af[ks], bfr, acc[nt], 0, 0, 0);
                }
            }

            if (gi < NLAYERS * NGRP - 1) {
                __syncthreads();             // B1: all waves done reading Wl
                // DMA next flat group (crosses layer boundary) + bias prefetch.
                const int l2 = (gi + 1) >> 4;
                const int g2 = (gi + 1) & 15;
                const unsigned short* src = wom +
                    ((size_t)l2 * NCOL + (size_t)g2 * GRP) * WID + ln * 8;
                #pragma unroll
                for (int i = 0; i < 6; ++i) {
                    const int c = wv + 4 * i;
                    if (c < 23) stage16(src + c * 512, Wl + c * 512);
                }
                #pragma unroll
                for (int nt = 0; nt < 6; ++nt) {
                    int o = g2 * GRP + nt * 16 + m;
                    o = (o < NCOL) ? o : (NCOL - 1);
                    bnx[nt] = bo[(size_t)l2 * NCOL + o] * LOG2E;
                }
            }

            // P -> Pc ROW-major view of S: row (q*4+rr), col offn[nt].
            #pragma unroll
            for (int nt = 0; nt < 6; ++nt) {
                const int cb = q * 4 * PCP + offn[nt];
                unsigned int p0 = cvtpk_bf16(acc[nt][0], acc[nt][1]);
                unsigned int p1 = cvtpk_bf16(acc[nt][2], acc[nt][3]);
                sw[cb          ] = (unsigned short)p0;
                sw[cb +     PCP] = (unsigned short)(p0 >> 16);
                sw[cb + 2 * PCP] = (unsigned short)p1;
                sw[cb + 3 * PCP] = (unsigned short)(p1 >> 16);
            }
            asm volatile("" ::: "memory");   // pin Pc stores before pp loads

            // ---- spline: 4 dims x 16 rows, lane = (b=m, dim q). pp is
            //      pre-scaled by log2e: exp2f(pp) == e^{P_raw}. ----
            {
                const int d = g * 4 + q;

                // 3x b128: row m, cols q*24 .. q*24+23 (23 used + 1 pad).
                const unsigned short* pr = &sw[m * PCP + q * 24];
                u16x8 w0 = *(const u16x8*)(pr);
                u16x8 w1 = *(const u16x8*)(pr + 8);
                u16x8 w2 = *(const u16x8*)(pr + 16);
                uint4 r0 = __builtin_bit_cast(uint4, w0);
                uint4 r1 = __builtin_bit_cast(uint4, w1);
                uint4 r2 = __builtin_bit_cast(uint4, w2);

                float pp[NP];
                pp[0]  = bfLO(r0.x); pp[1]  = bfHI(r0.x);
                pp[2]  = bfLO(r0.y); pp[3]  = bfHI(r0.y);
                pp[4]  = bfLO(r0.z); pp[5]  = bfHI(r0.z);
                pp[6]  = bfLO(r0.w); pp[7]  = bfHI(r0.w);
                pp[8]  = bfLO(r1.x); pp[9]  = bfHI(r1.x);
                pp[10] = bfLO(r1.y); pp[11] = bfHI(r1.y);
                pp[12] = bfLO(r1.z); pp[13] = bfHI(r1.z);
                pp[14] = bfLO(r1.w); pp[15] = bfHI(r1.w);
                pp[16] = bfLO(r2.x); pp[17] = bfHI(r2.x);
                pp[18] = bfLO(r2.y); pp[19] = bfHI(r2.y);
                pp[20] = bfLO(r2.z); pp[21] = bfHI(r2.z);
                pp[22] = bfLO(r2.w);

                const float xraw = Xf[cur][wv][m][d];

                float ew[KN], eh[KN];
                #pragma unroll
                for (int j = 0; j < KN; ++j) {
                    ew[j] = exp2f(pp[j]);
                    eh[j] = exp2f(pp[8 + j]);
                }
                const float sw_ = ((ew[0] + ew[1]) + (ew[2] + ew[3]))
                                + ((ew[4] + ew[5]) + (ew[6] + ew[7]));
                const float sh_ = ((eh[0] + eh[1]) + (eh[2] + eh[3]))
                                + ((eh[4] + eh[5]) + (eh[6] + eh[7]));
                const float cmul = 8.0f / 1.01f;     // 2*Bi/(1+ADJ)
                const float cadd = 0.00125f * (8.0f / 1.01f);
                const float rw = cmul / sw_, rh = cmul / sh_;
                float width[KN], height[KN];
                #pragma unroll
                for (int j = 0; j < KN; ++j) {
                    width[j]  = fmaf(ew[j], rw, cadd);
                    height[j] = fmaf(eh[j], rh, cadd);
                }

                const bool inside = (xraw > -BI_F) && (xraw < BI_F);
                const float xcl = fminf(fmaxf(xraw, -BI_F), BI_F);

                // Knot scan, i=0 peeled (xcl >= -Bi always). Tracks the two
                // SELECTED raw derivative params; softplus deferred to the 2
                // selected values. cc is monotone non-increasing in i, so
                // cc1 <=> k>=1 and cc7 <=> k==7 (boundary derivs = 1.0).
                float cx = -BI_F + width[0], cy = -BI_F + height[0];
                float xk = -BI_F, yk = -BI_F, xk1 = cx, yk1 = cy;
                float selk = pp[16], selk1 = pp[16];
                bool cc1 = false, cc7 = false;
                #pragma unroll
                for (int i = 1; i < KN; ++i) {
                    const float nx = cx + width[i];
                    const float ny = cy + height[i];
                    const bool cc = (xcl >= cx);
                    if (i == 1) cc1 = cc;
                    if (i == 7) cc7 = cc;
                    xk  = cc ? cx : xk;    yk  = cc ? cy : yk;
                    xk1 = cc ? nx : xk1;   yk1 = cc ? ny : yk1;
                    selk = cc ? pp[15 + i] : selk;
                    if (i < 7) selk1 = cc ? pp[16 + i] : selk1;
                    cx = nx; cy = ny;
                }
                // softplus(p)+0.001 on the two selected (log2e pre-baked).
                const float ta = exp2f(selk);
                const float da = fmaf(__log2f(1.0f + ta), 0.69314718f, 0.001f);
                const float tb = exp2f(selk1);
                const float db = fmaf(__log2f(1.0f + tb), 0.69314718f, 0.001f);
                const float dk  = cc1 ? da : 1.0f;
                const float dk1 = cc7 ? 1.0f : db;

                const float invw = 1.0f / (xk1 - xk);
                const float sk   = (yk1 - yk) * invw;
                const float xi   = (xcl - xk) * invw;
                const float omx  = 1.0f - xi;
                const float den  = sk + (dk1 + dk - 2.0f * sk) * xi * omx;
                const float rden = 1.0f / den;
                float outv = fmaf((yk1 - yk) * (sk * xi * xi + dk * xi * omx), rden, yk);
                const float numl = dk1 * xi * xi + 2.0f * sk * xi * omx + dk * omx * omx;
                float ldj = __logf(sk * sk * numl * rden * rden);
                outv = inside ? outv : xraw;
                ldj  = inside ? ldj : 0.0f;

                // flipped write into next x buffer (wave-private rows)
                Xf[nxt][wv][m][DIMS - 1 - d] = outv;
                ldsum += ldj;
            }

            if (gi < NLAYERS * NGRP - 1) {
                __syncthreads();             // B2: drains DMA for all waves
            }
        }

        cur ^= 1;
    }

    asm volatile("" ::: "memory");

    // ---- epilogue: coalesced xout write from final Xf buffer ----
    {
        const int row = ln >> 2;
        const int c0  = (ln & 3) * 16;
        const float* srcr = &Xf[cur][wv][row][c0];
        float* dstr = xout + (size_t)(r0 + row) * DIMS + c0;
        #pragma unroll
        for (int i = 0; i < 4; ++i)
            *(float4*)(dstr + i * 4) = *(const float4*)(srcr + i * 4);
    }

    // ---- ld: reduce q-quarters, ONE plain store per row (exclusive owner,
    //      overwrites harness poison) ----
    float v = ldsum + __shfl_xor(ldsum, 16, 64);
    v = v + __shfl_xor(v, 32, 64);
    if (ln < 16) {
        ldp[r0 + ln] = v;
    }
}

// ---------------------------------------------------------------------------
extern "C" void kernel_launch(void* const* d_in, const int* in_sizes, int n_in,
                              void* d_out, int out_size, void* d_ws, size_t ws_size,
                              hipStream_t stream)
{
    const float* x      = (const float*)d_in[0];
    const float* y      = (const float*)d_in[1];
    const float* f_W1   = (const float*)d_in[2];
    const float* f_b1   = (const float*)d_in[3];
    const float* f_Wout = (const float*)d_in[4];
    const float* f_bout = (const float*)d_in[5];
    const float* g_W1   = (const float*)d_in[6];
    const float* g_b1   = (const float*)d_in[7];
    const float* g_Wout = (const float*)d_in[8];
    const float* g_bout = (const float*)d_in[9];

    float* out = (float*)d_out;
    float* xo  = out;                               // [B, D]
    float* ldf = out + (size_t)BATCH * DIMS;        // [B]
    float* yo  = ldf + BATCH;                       // [B, D]
    float* ldg = yo + (size_t)BATCH * DIMS;         // [B]

    // Workspace: womask + w1mask only.
    unsigned short* womask = (unsigned short*)d_ws;           // 2*PF_WOUT bf16
    unsigned short* w1mask = womask + 2 * (size_t)PF_WOUT;    // 2*PF_W1 bf16

    premask_kernel<<<dim3(2048), dim3(256), 0, stream>>>(
        f_Wout, g_Wout, f_W1, g_W1, womask, w1mask);

    flow8_kernel<<<dim3(BATCH / 64, 2), dim3(256), 0, stream>>>(
        x, y, xo, yo,
        w1mask, w1mask + (size_t)PF_W1,
        f_b1, g_b1,
        womask, womask + (size_t)PF_WOUT,
        f_bout, g_bout,
        ldf, ldg);
}